// Round 8
// baseline (7998.455 us; speedup 1.0000x reference)
//
#include <hip/hip_runtime.h>

#define TS    576
#define HID   128
#define GT    512       // 4*HID
#define GTP   640       // padded part stride -> LDS/wg > 80KB -> 1 wg/CU -> 256-VGPR budget
#define K0    144       // 15 x (emb-folded) | 128 h0 | 1 zero pad
#define BB    8         // batch rows per block
#define NT    512       // 8 waves -> 2 waves/SIMD (1 wg/CU via LDS)
#define TS128 (TS*HID)  // 73728

// prepped weights (k-major, gate-interleaved columns jn = unit*4 + gate)
__device__ float g_wt0[K0 * GT];     // [k][col]: k 0..14 x-proj (emb folded), 15..142 h, 143 zero
__device__ float g_b0[GT];
__device__ float g_wih1[HID * GT];   // [k][col]
__device__ float g_whh1[HID * GT];   // [k][col]
__device__ float g_b1[GT];
__device__ float g_out0[2048 * TS * HID];   // 604 MB intermediate: out0[b][t][128]

__global__ void prep_kernel(const float* __restrict__ W_emb, const float* __restrict__ b_emb,
                            const float* __restrict__ W_ih0, const float* __restrict__ W_hh0,
                            const float* __restrict__ b_ih0, const float* __restrict__ b_hh0,
                            const float* __restrict__ W_ih1, const float* __restrict__ W_hh1,
                            const float* __restrict__ b_ih1, const float* __restrict__ b_hh1)
{
    const int jo = blockIdx.x * blockDim.x + threadIdx.x;
    if (jo >= GT) return;
    const int g  = jo >> 7;         // gate 0..3 (i,f,g,o)
    const int u  = jo & 127;        // unit
    const int jn = (u << 2) | g;    // interleaved column

    // L0: fold embedding into x-projection
    for (int i = 0; i < 15; ++i) {
        float s = 0.f;
        for (int c = 0; c < 32; ++c) s = fmaf(W_ih0[jo*32 + c], W_emb[c*15 + i], s);
        g_wt0[i*GT + jn] = s;
    }
    for (int k = 0; k < HID; ++k) g_wt0[(15 + k)*GT + jn] = W_hh0[jo*HID + k];
    g_wt0[143*GT + jn] = 0.f;
    float bb = b_ih0[jo] + b_hh0[jo];
    for (int c = 0; c < 32; ++c) bb = fmaf(W_ih0[jo*32 + c], b_emb[c], bb);
    g_b0[jn] = bb;

    for (int k = 0; k < HID; ++k) g_wih1[k*GT + jn] = W_ih1[jo*HID + k];
    for (int k = 0; k < HID; ++k) g_whh1[k*GT + jn] = W_hh1[jo*HID + k];
    g_b1[jn] = b_ih1[jo] + b_hh1[jo];
}

__device__ __forceinline__ float sigm(float v) { return 1.f / (1.f + __expf(-v)); }

#define LD4(P_) (*(const float4*)(P_))
// macro params must never be named x/y/z/w/a/s
#define FMARC(A_, SV_, W_) \
    A_.x = fmaf(SV_, W_.x, A_.x); A_.y = fmaf(SV_, W_.y, A_.y); \
    A_.z = fmaf(SV_, W_.z, A_.z); A_.w = fmaf(SV_, W_.w, A_.w);

// ============================ Kernel A: layer-0 ============================
// LDS 86.5KB > 81.9KB -> only 1 wg/CU fits -> LDS-derived occupancy 2 waves/EU
// -> RA VGPR budget 256 -> the 144 weight VGPRs stay resident (r5/r6: 76KB LDS
// allowed 2 wg/CU -> budget pinned 128 -> weights rematerialized from L2).
__global__ void __attribute__((amdgpu_flat_work_group_size(NT, NT), amdgpu_waves_per_eu(2, 2)))
lstm_l0(const float* __restrict__ x, float* __restrict__ out0)
{
    __shared__ float src0[BB][K0];      // [15 x | 128 h0 | 1 pad]  4.6 KB
    __shared__ float part[4][BB][GTP];  // 4-way k-split partials    80 KB

    const int tid  = threadIdx.x;
    const int cg   = tid & 127;
    const int q4   = cg << 2;
    const int ks   = tid >> 7;          // 0..3, wave-uniform
    const int um   = cg;                // update unit
    const int rlo  = tid >> 7;          // update rows rlo and rlo+4
    const int row0 = blockIdx.x * BB;
    const int k0b  = ks * 36;

    // persistent weights: 36 named float4 (144 VGPRs)
    const float* p0 = g_wt0 + (size_t)k0b * GT + q4;
#define DECLA(I_) const float4 wa##I_ = LD4(p0 + (I_)*GT);
    DECLA(0)  DECLA(1)  DECLA(2)  DECLA(3)  DECLA(4)  DECLA(5)
    DECLA(6)  DECLA(7)  DECLA(8)  DECLA(9)  DECLA(10) DECLA(11)
    DECLA(12) DECLA(13) DECLA(14) DECLA(15) DECLA(16) DECLA(17)
    DECLA(18) DECLA(19) DECLA(20) DECLA(21) DECLA(22) DECLA(23)
    DECLA(24) DECLA(25) DECLA(26) DECLA(27) DECLA(28) DECLA(29)
    DECLA(30) DECLA(31) DECLA(32) DECLA(33) DECLA(34) DECLA(35)

    const float4 zz = make_float4(0.f, 0.f, 0.f, 0.f);
    const float4 i0 = (ks == 0) ? LD4(g_b0 + q4) : zz;
    float c_a = 0.f, c_b = 0.f;

    for (int i = tid; i < BB*K0; i += NT) (&src0[0][0])[i] = 0.f;

    const int lr = tid / 15, li = tid - lr * 15;
    const float* xp = x + (size_t)(row0 + (tid < 120 ? lr : 0)) * (TS * 15) + (tid < 120 ? li : 0);

    __syncthreads();
    if (tid < 120) src0[lr][li] = xp[0];
    __syncthreads();

    float* pp = &part[ks][0][0];

#define L0R(R_) { \
    const float* sp_ = &src0[R_][k0b]; \
    const float4 s0_ = LD4(sp_+0),  s1_ = LD4(sp_+4),  s2_ = LD4(sp_+8); \
    const float4 s3_ = LD4(sp_+12), s4_ = LD4(sp_+16), s5_ = LD4(sp_+20); \
    const float4 s6_ = LD4(sp_+24), s7_ = LD4(sp_+28), s8_ = LD4(sp_+32); \
    float4 acc_ = i0; \
    FMARC(acc_, s0_.x, wa0)  FMARC(acc_, s0_.y, wa1)  FMARC(acc_, s0_.z, wa2)  FMARC(acc_, s0_.w, wa3)  \
    FMARC(acc_, s1_.x, wa4)  FMARC(acc_, s1_.y, wa5)  FMARC(acc_, s1_.z, wa6)  FMARC(acc_, s1_.w, wa7)  \
    FMARC(acc_, s2_.x, wa8)  FMARC(acc_, s2_.y, wa9)  FMARC(acc_, s2_.z, wa10) FMARC(acc_, s2_.w, wa11) \
    FMARC(acc_, s3_.x, wa12) FMARC(acc_, s3_.y, wa13) FMARC(acc_, s3_.z, wa14) FMARC(acc_, s3_.w, wa15) \
    FMARC(acc_, s4_.x, wa16) FMARC(acc_, s4_.y, wa17) FMARC(acc_, s4_.z, wa18) FMARC(acc_, s4_.w, wa19) \
    FMARC(acc_, s5_.x, wa20) FMARC(acc_, s5_.y, wa21) FMARC(acc_, s5_.z, wa22) FMARC(acc_, s5_.w, wa23) \
    FMARC(acc_, s6_.x, wa24) FMARC(acc_, s6_.y, wa25) FMARC(acc_, s6_.z, wa26) FMARC(acc_, s6_.w, wa27) \
    FMARC(acc_, s7_.x, wa28) FMARC(acc_, s7_.y, wa29) FMARC(acc_, s7_.z, wa30) FMARC(acc_, s7_.w, wa31) \
    FMARC(acc_, s8_.x, wa32) FMARC(acc_, s8_.y, wa33) FMARC(acc_, s8_.z, wa34) FMARC(acc_, s8_.w, wa35) \
    *(float4*)(pp + (R_)*GTP + q4) = acc_; }

#define UPD0(R_, C_) { \
    const int ub_ = um << 2; \
    float4 gv_ = LD4(&part[0][R_][ub_]); \
    { const float4 p1_ = LD4(&part[1][R_][ub_]); gv_.x += p1_.x; gv_.y += p1_.y; gv_.z += p1_.z; gv_.w += p1_.w; } \
    { const float4 p2_ = LD4(&part[2][R_][ub_]); gv_.x += p2_.x; gv_.y += p2_.y; gv_.z += p2_.z; gv_.w += p2_.w; } \
    { const float4 p3_ = LD4(&part[3][R_][ub_]); gv_.x += p3_.x; gv_.y += p3_.y; gv_.z += p3_.z; gv_.w += p3_.w; } \
    const float iv_ = sigm(gv_.x), fv_ = sigm(gv_.y), ov_ = sigm(gv_.w); \
    const float gg_ = tanhf(gv_.z); \
    C_ = fmaf(fv_, C_, iv_ * gg_); \
    const float hv_ = ov_ * tanhf(C_); \
    src0[R_][15 + um] = hv_; \
    out0[(size_t)(row0 + (R_)) * TS128 + (size_t)t * HID + um] = hv_; }

    #pragma unroll 1
    for (int t = 0; t < TS; ++t) {
        float xnext = 0.f;
        if (tid < 120 && t + 1 < TS) xnext = xp[(size_t)(t + 1) * 15];
        L0R(0) L0R(1) L0R(2) L0R(3) L0R(4) L0R(5) L0R(6) L0R(7)
        __syncthreads();
        UPD0(rlo, c_a)
        { const int rhi_ = rlo + 4; UPD0(rhi_, c_b) }
        if (tid < 120 && t + 1 < TS) src0[lr][li] = xnext;
        __syncthreads();
    }
}

// ============================ Kernel C: layer-1 + FC head ============================
// LDS 94.2KB -> 1 wg/CU -> 256-VGPR budget (same mechanism as lstm_l0).
__global__ void __attribute__((amdgpu_flat_work_group_size(NT, NT), amdgpu_waves_per_eu(2, 2)))
lstm_l1(const float* __restrict__ out0,
        const float* __restrict__ W_fc1, const float* __restrict__ b_fc1,
        const float* __restrict__ W_fc2, const float* __restrict__ b_fc2,
        float* __restrict__ out)
{
    __shared__ float h1s[BB][HID];       // h1 state              4 KB
    __shared__ float obuf[2][BB][HID];   // out0[t] double buffer 8 KB
    __shared__ float part[4][BB][GTP];   // k-split partials     80 KB

    const int tid  = threadIdx.x;
    const int cg   = tid & 127;
    const int q4   = cg << 2;
    const int ks   = tid >> 7;
    const int um   = cg;
    const int rlo  = tid >> 7;
    const int row0 = blockIdx.x * BB;
    const int k1b  = ks * 32;

    // persistent W_hh1 slice: 32 named float4 (128 VGPRs)
    const float* ph = g_whh1 + (size_t)k1b * GT + q4;
#define DECLB(I_) const float4 wb##I_ = LD4(ph + (I_)*GT);
    DECLB(0)  DECLB(1)  DECLB(2)  DECLB(3)  DECLB(4)  DECLB(5)  DECLB(6)  DECLB(7)
    DECLB(8)  DECLB(9)  DECLB(10) DECLB(11) DECLB(12) DECLB(13) DECLB(14) DECLB(15)
    DECLB(16) DECLB(17) DECLB(18) DECLB(19) DECLB(20) DECLB(21) DECLB(22) DECLB(23)
    DECLB(24) DECLB(25) DECLB(26) DECLB(27) DECLB(28) DECLB(29) DECLB(30) DECLB(31)

    const float* pih = g_wih1 + (size_t)k1b * GT + q4;   // streamed per step (L2-resident)

    const float4 zz = make_float4(0.f, 0.f, 0.f, 0.f);
    const float4 i1 = (ks == 0) ? LD4(g_b1 + q4) : zz;
    float c_a = 0.f, c_b = 0.f;

    for (int i = tid; i < BB*HID; i += NT) (&h1s[0][0])[i] = 0.f;

    const int pr = tid >> 5, pk4 = (tid & 31) << 2;   // prefetch role (tid<256)
    float4 pf = zz;
    if (tid < 256) pf = LD4(out0 + (size_t)(row0 + pr) * TS128 + pk4);
    __syncthreads();
    if (tid < 256) *(float4*)(&obuf[0][pr][pk4]) = pf;
    __syncthreads();

    float* pp = &part[ks][0][0];

// stream-load 4 consecutive k-rows of W_ih1 into named regs
#define SWL(P_, J_) \
    P_##0 = LD4(pih + (size_t)(4*(J_)+0)*GT); \
    P_##1 = LD4(pih + (size_t)(4*(J_)+1)*GT); \
    P_##2 = LD4(pih + (size_t)(4*(J_)+2)*GT); \
    P_##3 = LD4(pih + (size_t)(4*(J_)+3)*GT);

// hh 4 k x 4 rows (RB_..RB_+3), accs AA_..AD_
#define HH4(J_, W0_, W1_, W2_, W3_, RB_, AA_, AB_, AC_, AD_) { \
    const float4 hA_ = LD4(&h1s[(RB_)+0][k1b + 4*(J_)]); \
    const float4 hB_ = LD4(&h1s[(RB_)+1][k1b + 4*(J_)]); \
    const float4 hC_ = LD4(&h1s[(RB_)+2][k1b + 4*(J_)]); \
    const float4 hD_ = LD4(&h1s[(RB_)+3][k1b + 4*(J_)]); \
    FMARC(AA_, hA_.x, W0_) FMARC(AA_, hA_.y, W1_) FMARC(AA_, hA_.z, W2_) FMARC(AA_, hA_.w, W3_) \
    FMARC(AB_, hB_.x, W0_) FMARC(AB_, hB_.y, W1_) FMARC(AB_, hB_.z, W2_) FMARC(AB_, hB_.w, W3_) \
    FMARC(AC_, hC_.x, W0_) FMARC(AC_, hC_.y, W1_) FMARC(AC_, hC_.z, W2_) FMARC(AC_, hC_.w, W3_) \
    FMARC(AD_, hD_.x, W0_) FMARC(AD_, hD_.y, W1_) FMARC(AD_, hD_.z, W2_) FMARC(AD_, hD_.w, W3_) }
#define HH(J_, W0_, W1_, W2_, W3_) \
    HH4(J_, W0_, W1_, W2_, W3_, 0, acc0, acc1, acc2, acc3) \
    HH4(J_, W0_, W1_, W2_, W3_, 4, acc4, acc5, acc6, acc7)

// ih 4 k (streamed regs P_##0..3) x 4 rows from obuf[t&1]
#define IH4(P_, J_, RB_, AA_, AB_, AC_, AD_) { \
    const float4 oA_ = LD4(ob + ((RB_)+0)*HID + k1b + 4*(J_)); \
    const float4 oB_ = LD4(ob + ((RB_)+1)*HID + k1b + 4*(J_)); \
    const float4 oC_ = LD4(ob + ((RB_)+2)*HID + k1b + 4*(J_)); \
    const float4 oD_ = LD4(ob + ((RB_)+3)*HID + k1b + 4*(J_)); \
    FMARC(AA_, oA_.x, P_##0) FMARC(AA_, oA_.y, P_##1) FMARC(AA_, oA_.z, P_##2) FMARC(AA_, oA_.w, P_##3) \
    FMARC(AB_, oB_.x, P_##0) FMARC(AB_, oB_.y, P_##1) FMARC(AB_, oB_.z, P_##2) FMARC(AB_, oB_.w, P_##3) \
    FMARC(AC_, oC_.x, P_##0) FMARC(AC_, oC_.y, P_##1) FMARC(AC_, oC_.z, P_##2) FMARC(AC_, oC_.w, P_##3) \
    FMARC(AD_, oD_.x, P_##0) FMARC(AD_, oD_.y, P_##1) FMARC(AD_, oD_.z, P_##2) FMARC(AD_, oD_.w, P_##3) }
#define IH(P_, J_) \
    IH4(P_, J_, 0, acc0, acc1, acc2, acc3) \
    IH4(P_, J_, 4, acc4, acc5, acc6, acc7)

#define UPD1(R_, C_) { \
    const int ub_ = um << 2; \
    float4 gv_ = LD4(&part[0][R_][ub_]); \
    { const float4 p1_ = LD4(&part[1][R_][ub_]); gv_.x += p1_.x; gv_.y += p1_.y; gv_.z += p1_.z; gv_.w += p1_.w; } \
    { const float4 p2_ = LD4(&part[2][R_][ub_]); gv_.x += p2_.x; gv_.y += p2_.y; gv_.z += p2_.z; gv_.w += p2_.w; } \
    { const float4 p3_ = LD4(&part[3][R_][ub_]); gv_.x += p3_.x; gv_.y += p3_.y; gv_.z += p3_.z; gv_.w += p3_.w; } \
    const float iv_ = sigm(gv_.x), fv_ = sigm(gv_.y), ov_ = sigm(gv_.w); \
    const float gg_ = tanhf(gv_.z); \
    C_ = fmaf(fv_, C_, iv_ * gg_); \
    h1s[R_][um] = ov_ * tanhf(C_); }

    #pragma unroll 1
    for (int t = 0; t < TS; ++t) {
        if (tid < 256 && t + 1 < TS)
            pf = LD4(out0 + (size_t)(row0 + pr) * TS128 + (size_t)(t + 1) * HID + pk4);

        const float* ob = &obuf[t & 1][0][0];
        float4 acc0 = i1, acc1 = i1, acc2 = i1, acc3 = i1;
        float4 acc4 = i1, acc5 = i1, acc6 = i1, acc7 = i1;
        float4 sa0, sa1, sa2, sa3, sb0, sb1, sb2, sb3;

        SWL(sa, 0) SWL(sb, 1)                  // stream chunks 0,1 in flight under hh-part
        HH(0, wb0,  wb1,  wb2,  wb3)
        HH(1, wb4,  wb5,  wb6,  wb7)
        HH(2, wb8,  wb9,  wb10, wb11)
        HH(3, wb12, wb13, wb14, wb15)
        HH(4, wb16, wb17, wb18, wb19)
        HH(5, wb20, wb21, wb22, wb23)
        HH(6, wb24, wb25, wb26, wb27)
        HH(7, wb28, wb29, wb30, wb31)
        IH(sa, 0) SWL(sa, 2)
        IH(sb, 1) SWL(sb, 3)
        IH(sa, 2) SWL(sa, 4)
        IH(sb, 3) SWL(sb, 5)
        IH(sa, 4) SWL(sa, 6)
        IH(sb, 5) SWL(sb, 7)
        IH(sa, 6)
        IH(sb, 7)

        *(float4*)(pp + 0*GTP + q4) = acc0;
        *(float4*)(pp + 1*GTP + q4) = acc1;
        *(float4*)(pp + 2*GTP + q4) = acc2;
        *(float4*)(pp + 3*GTP + q4) = acc3;
        *(float4*)(pp + 4*GTP + q4) = acc4;
        *(float4*)(pp + 5*GTP + q4) = acc5;
        *(float4*)(pp + 6*GTP + q4) = acc6;
        *(float4*)(pp + 7*GTP + q4) = acc7;
        __syncthreads();

        UPD1(rlo, c_a)
        { const int rhi_ = rlo + 4; UPD1(rhi_, c_b) }
        if (tid < 256 && t + 1 < TS) *(float4*)(&obuf[(t + 1) & 1][pr][pk4]) = pf;
        __syncthreads();
    }

    // ---- FC head: relu(h1 @ W_fc1^T + b_fc1) @ W_fc2^T + b_fc2 ----
    {
        const int rr = tid >> 6, u = tid & 63;   // 8 rows x 64 units = 512 threads
        float acc = b_fc1[u];
        #pragma unroll 8
        for (int k = 0; k < HID; ++k) acc = fmaf(h1s[rr][k], W_fc1[u*HID + k], acc);
        part[0][rr][u] = fmaxf(acc, 0.f);
    }
    __syncthreads();
    if (tid < BB) {
        float acc = b_fc2[0];
        #pragma unroll 8
        for (int u = 0; u < 64; ++u) acc = fmaf(part[0][tid][u], W_fc2[u], acc);
        out[row0 + tid] = acc;
    }
}

extern "C" void kernel_launch(void* const* d_in, const int* in_sizes, int n_in,
                              void* d_out, int out_size, void* d_ws, size_t ws_size,
                              hipStream_t stream)
{
    const float* x     = (const float*)d_in[0];
    const float* W_emb = (const float*)d_in[1];
    const float* b_emb = (const float*)d_in[2];
    const float* W_ih0 = (const float*)d_in[3];
    const float* W_hh0 = (const float*)d_in[4];
    const float* b_ih0 = (const float*)d_in[5];
    const float* b_hh0 = (const float*)d_in[6];
    const float* W_ih1 = (const float*)d_in[7];
    const float* W_hh1 = (const float*)d_in[8];
    const float* b_ih1 = (const float*)d_in[9];
    const float* b_hh1 = (const float*)d_in[10];
    const float* W_fc1 = (const float*)d_in[11];
    const float* b_fc1 = (const float*)d_in[12];
    const float* W_fc2 = (const float*)d_in[13];
    const float* b_fc2 = (const float*)d_in[14];
    float* out = (float*)d_out;

    float* out0;
    hipGetSymbolAddress((void**)&out0, HIP_SYMBOL(g_out0));

    prep_kernel<<<2, 256, 0, stream>>>(W_emb, b_emb, W_ih0, W_hh0, b_ih0, b_hh0,
                                       W_ih1, W_hh1, b_ih1, b_hh1);
    lstm_l0<<<2048 / BB, NT, 0, stream>>>(x, out0);
    lstm_l1<<<2048 / BB, NT, 0, stream>>>(out0, W_fc1, b_fc1, W_fc2, b_fc2, out);
}

// Round 9
// 7995.981 us; speedup vs baseline: 1.0003x; 1.0003x over previous
//
#include <hip/hip_runtime.h>

#define TS    576
#define HID   128
#define GT    512       // 4*HID
#define GTP   640       // padded part stride -> LDS/wg > 80KB -> 1 wg/CU -> 256-VGPR budget
#define K0    144       // 15 x (emb-folded) | 128 h0 | 1 zero pad
#define BB    8         // batch rows per block
#define NT    512       // 8 waves -> 2 waves/SIMD (1 wg/CU via LDS)
#define TS128 (TS*HID)  // 73728

// prepped weights (k-major, gate-interleaved columns jn = unit*4 + gate)
__device__ float g_wt0[K0 * GT];     // [k][col]: k 0..14 x-proj (emb folded), 15..142 h, 143 zero
__device__ float g_b0[GT];
__device__ float g_wih1[HID * GT];   // [k][col]
__device__ float g_whh1[HID * GT];   // [k][col]
__device__ float g_b1[GT];
__device__ float g_out0[2048 * TS * HID];   // 604 MB intermediate: out0[b][t][128]

__global__ void prep_kernel(const float* __restrict__ W_emb, const float* __restrict__ b_emb,
                            const float* __restrict__ W_ih0, const float* __restrict__ W_hh0,
                            const float* __restrict__ b_ih0, const float* __restrict__ b_hh0,
                            const float* __restrict__ W_ih1, const float* __restrict__ W_hh1,
                            const float* __restrict__ b_ih1, const float* __restrict__ b_hh1)
{
    const int jo = blockIdx.x * blockDim.x + threadIdx.x;
    if (jo >= GT) return;
    const int g  = jo >> 7;         // gate 0..3 (i,f,g,o)
    const int u  = jo & 127;        // unit
    const int jn = (u << 2) | g;    // interleaved column

    // L0: fold embedding into x-projection
    for (int i = 0; i < 15; ++i) {
        float s = 0.f;
        for (int c = 0; c < 32; ++c) s = fmaf(W_ih0[jo*32 + c], W_emb[c*15 + i], s);
        g_wt0[i*GT + jn] = s;
    }
    for (int k = 0; k < HID; ++k) g_wt0[(15 + k)*GT + jn] = W_hh0[jo*HID + k];
    g_wt0[143*GT + jn] = 0.f;
    float bb = b_ih0[jo] + b_hh0[jo];
    for (int c = 0; c < 32; ++c) bb = fmaf(W_ih0[jo*32 + c], b_emb[c], bb);
    g_b0[jn] = bb;

    for (int k = 0; k < HID; ++k) g_wih1[k*GT + jn] = W_ih1[jo*HID + k];
    for (int k = 0; k < HID; ++k) g_whh1[k*GT + jn] = W_hh1[jo*HID + k];
    g_b1[jn] = b_ih1[jo] + b_hh1[jo];
}

__device__ __forceinline__ float sigm(float v) { return 1.f / (1.f + __expf(-v)); }

#define LD4(P_) (*(const float4*)(P_))
// macro params must never be named x/y/z/w/a/s
#define FMARC(A_, SV_, W_) \
    A_.x = fmaf(SV_, W_.x, A_.x); A_.y = fmaf(SV_, W_.y, A_.y); \
    A_.z = fmaf(SV_, W_.z, A_.z); A_.w = fmaf(SV_, W_.w, A_.w);

// ============================ Kernel A: layer-0 ============================
// LDS 86.5KB > 81.9KB -> only 1 wg/CU fits -> LDS-derived occupancy 2 waves/EU
// -> RA VGPR budget 256 -> the 144 weight VGPRs stay resident (r5/r6: 76KB LDS
// allowed 2 wg/CU -> budget pinned 128 -> weights rematerialized from L2).
__global__ void __attribute__((amdgpu_flat_work_group_size(NT, NT), amdgpu_waves_per_eu(2, 2)))
lstm_l0(const float* __restrict__ x, float* __restrict__ out0)
{
    __shared__ float src0[BB][K0];      // [15 x | 128 h0 | 1 pad]  4.6 KB
    __shared__ float part[4][BB][GTP];  // 4-way k-split partials    80 KB

    const int tid  = threadIdx.x;
    const int cg   = tid & 127;
    const int q4   = cg << 2;
    const int ks   = tid >> 7;          // 0..3, wave-uniform
    const int um   = cg;                // update unit
    const int rlo  = tid >> 7;          // update rows rlo and rlo+4
    const int row0 = blockIdx.x * BB;
    const int k0b  = ks * 36;

    // persistent weights: 36 named float4 (144 VGPRs)
    const float* p0 = g_wt0 + (size_t)k0b * GT + q4;
#define DECLA(I_) const float4 wa##I_ = LD4(p0 + (I_)*GT);
    DECLA(0)  DECLA(1)  DECLA(2)  DECLA(3)  DECLA(4)  DECLA(5)
    DECLA(6)  DECLA(7)  DECLA(8)  DECLA(9)  DECLA(10) DECLA(11)
    DECLA(12) DECLA(13) DECLA(14) DECLA(15) DECLA(16) DECLA(17)
    DECLA(18) DECLA(19) DECLA(20) DECLA(21) DECLA(22) DECLA(23)
    DECLA(24) DECLA(25) DECLA(26) DECLA(27) DECLA(28) DECLA(29)
    DECLA(30) DECLA(31) DECLA(32) DECLA(33) DECLA(34) DECLA(35)

    const float4 zz = make_float4(0.f, 0.f, 0.f, 0.f);
    const float4 i0 = (ks == 0) ? LD4(g_b0 + q4) : zz;
    float c_a = 0.f, c_b = 0.f;

    for (int i = tid; i < BB*K0; i += NT) (&src0[0][0])[i] = 0.f;

    const int lr = tid / 15, li = tid - lr * 15;
    const float* xp = x + (size_t)(row0 + (tid < 120 ? lr : 0)) * (TS * 15) + (tid < 120 ? li : 0);

    __syncthreads();
    if (tid < 120) src0[lr][li] = xp[0];
    __syncthreads();

    float* pp = &part[ks][0][0];

#define L0R(R_) { \
    const float* sp_ = &src0[R_][k0b]; \
    const float4 s0_ = LD4(sp_+0),  s1_ = LD4(sp_+4),  s2_ = LD4(sp_+8); \
    const float4 s3_ = LD4(sp_+12), s4_ = LD4(sp_+16), s5_ = LD4(sp_+20); \
    const float4 s6_ = LD4(sp_+24), s7_ = LD4(sp_+28), s8_ = LD4(sp_+32); \
    float4 acc_ = i0; \
    FMARC(acc_, s0_.x, wa0)  FMARC(acc_, s0_.y, wa1)  FMARC(acc_, s0_.z, wa2)  FMARC(acc_, s0_.w, wa3)  \
    FMARC(acc_, s1_.x, wa4)  FMARC(acc_, s1_.y, wa5)  FMARC(acc_, s1_.z, wa6)  FMARC(acc_, s1_.w, wa7)  \
    FMARC(acc_, s2_.x, wa8)  FMARC(acc_, s2_.y, wa9)  FMARC(acc_, s2_.z, wa10) FMARC(acc_, s2_.w, wa11) \
    FMARC(acc_, s3_.x, wa12) FMARC(acc_, s3_.y, wa13) FMARC(acc_, s3_.z, wa14) FMARC(acc_, s3_.w, wa15) \
    FMARC(acc_, s4_.x, wa16) FMARC(acc_, s4_.y, wa17) FMARC(acc_, s4_.z, wa18) FMARC(acc_, s4_.w, wa19) \
    FMARC(acc_, s5_.x, wa20) FMARC(acc_, s5_.y, wa21) FMARC(acc_, s5_.z, wa22) FMARC(acc_, s5_.w, wa23) \
    FMARC(acc_, s6_.x, wa24) FMARC(acc_, s6_.y, wa25) FMARC(acc_, s6_.z, wa26) FMARC(acc_, s6_.w, wa27) \
    FMARC(acc_, s7_.x, wa28) FMARC(acc_, s7_.y, wa29) FMARC(acc_, s7_.z, wa30) FMARC(acc_, s7_.w, wa31) \
    FMARC(acc_, s8_.x, wa32) FMARC(acc_, s8_.y, wa33) FMARC(acc_, s8_.z, wa34) FMARC(acc_, s8_.w, wa35) \
    *(float4*)(pp + (R_)*GTP + q4) = acc_; }

#define UPD0(R_, C_) { \
    const int ub_ = um << 2; \
    float4 gv_ = LD4(&part[0][R_][ub_]); \
    { const float4 p1_ = LD4(&part[1][R_][ub_]); gv_.x += p1_.x; gv_.y += p1_.y; gv_.z += p1_.z; gv_.w += p1_.w; } \
    { const float4 p2_ = LD4(&part[2][R_][ub_]); gv_.x += p2_.x; gv_.y += p2_.y; gv_.z += p2_.z; gv_.w += p2_.w; } \
    { const float4 p3_ = LD4(&part[3][R_][ub_]); gv_.x += p3_.x; gv_.y += p3_.y; gv_.z += p3_.z; gv_.w += p3_.w; } \
    const float iv_ = sigm(gv_.x), fv_ = sigm(gv_.y), ov_ = sigm(gv_.w); \
    const float gg_ = tanhf(gv_.z); \
    C_ = fmaf(fv_, C_, iv_ * gg_); \
    const float hv_ = ov_ * tanhf(C_); \
    src0[R_][15 + um] = hv_; \
    out0[(size_t)(row0 + (R_)) * TS128 + (size_t)t * HID + um] = hv_; }

    #pragma unroll 1
    for (int t = 0; t < TS; ++t) {
        float xnext = 0.f;
        if (tid < 120 && t + 1 < TS) xnext = xp[(size_t)(t + 1) * 15];
        L0R(0) L0R(1) L0R(2) L0R(3) L0R(4) L0R(5) L0R(6) L0R(7)
        __syncthreads();
        UPD0(rlo, c_a)
        { const int rhi_ = rlo + 4; UPD0(rhi_, c_b) }
        if (tid < 120 && t + 1 < TS) src0[lr][li] = xnext;
        __syncthreads();
    }
}

// ============================ Kernel C: layer-1 + FC head ============================
// LDS 94.2KB -> 1 wg/CU -> 256-VGPR budget (same mechanism as lstm_l0).
__global__ void __attribute__((amdgpu_flat_work_group_size(NT, NT), amdgpu_waves_per_eu(2, 2)))
lstm_l1(const float* __restrict__ out0,
        const float* __restrict__ W_fc1, const float* __restrict__ b_fc1,
        const float* __restrict__ W_fc2, const float* __restrict__ b_fc2,
        float* __restrict__ out)
{
    __shared__ float h1s[BB][HID];       // h1 state              4 KB
    __shared__ float obuf[2][BB][HID];   // out0[t] double buffer 8 KB
    __shared__ float part[4][BB][GTP];   // k-split partials     80 KB

    const int tid  = threadIdx.x;
    const int cg   = tid & 127;
    const int q4   = cg << 2;
    const int ks   = tid >> 7;
    const int um   = cg;
    const int rlo  = tid >> 7;
    const int row0 = blockIdx.x * BB;
    const int k1b  = ks * 32;

    // persistent W_hh1 slice: 32 named float4 (128 VGPRs)
    const float* ph = g_whh1 + (size_t)k1b * GT + q4;
#define DECLB(I_) const float4 wb##I_ = LD4(ph + (I_)*GT);
    DECLB(0)  DECLB(1)  DECLB(2)  DECLB(3)  DECLB(4)  DECLB(5)  DECLB(6)  DECLB(7)
    DECLB(8)  DECLB(9)  DECLB(10) DECLB(11) DECLB(12) DECLB(13) DECLB(14) DECLB(15)
    DECLB(16) DECLB(17) DECLB(18) DECLB(19) DECLB(20) DECLB(21) DECLB(22) DECLB(23)
    DECLB(24) DECLB(25) DECLB(26) DECLB(27) DECLB(28) DECLB(29) DECLB(30) DECLB(31)

    const float* pih = g_wih1 + (size_t)k1b * GT + q4;   // streamed per step (L2-resident)

    const float4 zz = make_float4(0.f, 0.f, 0.f, 0.f);
    const float4 i1 = (ks == 0) ? LD4(g_b1 + q4) : zz;
    float c_a = 0.f, c_b = 0.f;

    for (int i = tid; i < BB*HID; i += NT) (&h1s[0][0])[i] = 0.f;

    const int pr = tid >> 5, pk4 = (tid & 31) << 2;   // prefetch role (tid<256)
    float4 pf = zz;
    if (tid < 256) pf = LD4(out0 + (size_t)(row0 + pr) * TS128 + pk4);
    __syncthreads();
    if (tid < 256) *(float4*)(&obuf[0][pr][pk4]) = pf;
    __syncthreads();

    float* pp = &part[ks][0][0];

// stream-load 4 consecutive k-rows of W_ih1 into named regs
#define SWL(P_, J_) \
    P_##0 = LD4(pih + (size_t)(4*(J_)+0)*GT); \
    P_##1 = LD4(pih + (size_t)(4*(J_)+1)*GT); \
    P_##2 = LD4(pih + (size_t)(4*(J_)+2)*GT); \
    P_##3 = LD4(pih + (size_t)(4*(J_)+3)*GT);

// hh 4 k x 4 rows (RB_..RB_+3), accs AA_..AD_
#define HH4(J_, W0_, W1_, W2_, W3_, RB_, AA_, AB_, AC_, AD_) { \
    const float4 hA_ = LD4(&h1s[(RB_)+0][k1b + 4*(J_)]); \
    const float4 hB_ = LD4(&h1s[(RB_)+1][k1b + 4*(J_)]); \
    const float4 hC_ = LD4(&h1s[(RB_)+2][k1b + 4*(J_)]); \
    const float4 hD_ = LD4(&h1s[(RB_)+3][k1b + 4*(J_)]); \
    FMARC(AA_, hA_.x, W0_) FMARC(AA_, hA_.y, W1_) FMARC(AA_, hA_.z, W2_) FMARC(AA_, hA_.w, W3_) \
    FMARC(AB_, hB_.x, W0_) FMARC(AB_, hB_.y, W1_) FMARC(AB_, hB_.z, W2_) FMARC(AB_, hB_.w, W3_) \
    FMARC(AC_, hC_.x, W0_) FMARC(AC_, hC_.y, W1_) FMARC(AC_, hC_.z, W2_) FMARC(AC_, hC_.w, W3_) \
    FMARC(AD_, hD_.x, W0_) FMARC(AD_, hD_.y, W1_) FMARC(AD_, hD_.z, W2_) FMARC(AD_, hD_.w, W3_) }
#define HH(J_, W0_, W1_, W2_, W3_) \
    HH4(J_, W0_, W1_, W2_, W3_, 0, acc0, acc1, acc2, acc3) \
    HH4(J_, W0_, W1_, W2_, W3_, 4, acc4, acc5, acc6, acc7)

// ih 4 k (streamed regs P_##0..3) x 4 rows from obuf[t&1]
#define IH4(P_, J_, RB_, AA_, AB_, AC_, AD_) { \
    const float4 oA_ = LD4(ob + ((RB_)+0)*HID + k1b + 4*(J_)); \
    const float4 oB_ = LD4(ob + ((RB_)+1)*HID + k1b + 4*(J_)); \
    const float4 oC_ = LD4(ob + ((RB_)+2)*HID + k1b + 4*(J_)); \
    const float4 oD_ = LD4(ob + ((RB_)+3)*HID + k1b + 4*(J_)); \
    FMARC(AA_, oA_.x, P_##0) FMARC(AA_, oA_.y, P_##1) FMARC(AA_, oA_.z, P_##2) FMARC(AA_, oA_.w, P_##3) \
    FMARC(AB_, oB_.x, P_##0) FMARC(AB_, oB_.y, P_##1) FMARC(AB_, oB_.z, P_##2) FMARC(AB_, oB_.w, P_##3) \
    FMARC(AC_, oC_.x, P_##0) FMARC(AC_, oC_.y, P_##1) FMARC(AC_, oC_.z, P_##2) FMARC(AC_, oC_.w, P_##3) \
    FMARC(AD_, oD_.x, P_##0) FMARC(AD_, oD_.y, P_##1) FMARC(AD_, oD_.z, P_##2) FMARC(AD_, oD_.w, P_##3) }
#define IH(P_, J_) \
    IH4(P_, J_, 0, acc0, acc1, acc2, acc3) \
    IH4(P_, J_, 4, acc4, acc5, acc6, acc7)

#define UPD1(R_, C_) { \
    const int ub_ = um << 2; \
    float4 gv_ = LD4(&part[0][R_][ub_]); \
    { const float4 p1_ = LD4(&part[1][R_][ub_]); gv_.x += p1_.x; gv_.y += p1_.y; gv_.z += p1_.z; gv_.w += p1_.w; } \
    { const float4 p2_ = LD4(&part[2][R_][ub_]); gv_.x += p2_.x; gv_.y += p2_.y; gv_.z += p2_.z; gv_.w += p2_.w; } \
    { const float4 p3_ = LD4(&part[3][R_][ub_]); gv_.x += p3_.x; gv_.y += p3_.y; gv_.z += p3_.z; gv_.w += p3_.w; } \
    const float iv_ = sigm(gv_.x), fv_ = sigm(gv_.y), ov_ = sigm(gv_.w); \
    const float gg_ = tanhf(gv_.z); \
    C_ = fmaf(fv_, C_, iv_ * gg_); \
    h1s[R_][um] = ov_ * tanhf(C_); }

    #pragma unroll 1
    for (int t = 0; t < TS; ++t) {
        if (tid < 256 && t + 1 < TS)
            pf = LD4(out0 + (size_t)(row0 + pr) * TS128 + (size_t)(t + 1) * HID + pk4);

        const float* ob = &obuf[t & 1][0][0];
        float4 acc0 = i1, acc1 = i1, acc2 = i1, acc3 = i1;
        float4 acc4 = i1, acc5 = i1, acc6 = i1, acc7 = i1;
        float4 sa0, sa1, sa2, sa3, sb0, sb1, sb2, sb3;

        SWL(sa, 0) SWL(sb, 1)                  // stream chunks 0,1 in flight under hh-part
        HH(0, wb0,  wb1,  wb2,  wb3)
        HH(1, wb4,  wb5,  wb6,  wb7)
        HH(2, wb8,  wb9,  wb10, wb11)
        HH(3, wb12, wb13, wb14, wb15)
        HH(4, wb16, wb17, wb18, wb19)
        HH(5, wb20, wb21, wb22, wb23)
        HH(6, wb24, wb25, wb26, wb27)
        HH(7, wb28, wb29, wb30, wb31)
        IH(sa, 0) SWL(sa, 2)
        IH(sb, 1) SWL(sb, 3)
        IH(sa, 2) SWL(sa, 4)
        IH(sb, 3) SWL(sb, 5)
        IH(sa, 4) SWL(sa, 6)
        IH(sb, 5) SWL(sb, 7)
        IH(sa, 6)
        IH(sb, 7)

        *(float4*)(pp + 0*GTP + q4) = acc0;
        *(float4*)(pp + 1*GTP + q4) = acc1;
        *(float4*)(pp + 2*GTP + q4) = acc2;
        *(float4*)(pp + 3*GTP + q4) = acc3;
        *(float4*)(pp + 4*GTP + q4) = acc4;
        *(float4*)(pp + 5*GTP + q4) = acc5;
        *(float4*)(pp + 6*GTP + q4) = acc6;
        *(float4*)(pp + 7*GTP + q4) = acc7;
        __syncthreads();

        UPD1(rlo, c_a)
        { const int rhi_ = rlo + 4; UPD1(rhi_, c_b) }
        if (tid < 256 && t + 1 < TS) *(float4*)(&obuf[(t + 1) & 1][pr][pk4]) = pf;
        __syncthreads();
    }

    // ---- FC head: relu(h1 @ W_fc1^T + b_fc1) @ W_fc2^T + b_fc2 ----
    {
        const int rr = tid >> 6, u = tid & 63;   // 8 rows x 64 units = 512 threads
        float acc = b_fc1[u];
        #pragma unroll 8
        for (int k = 0; k < HID; ++k) acc = fmaf(h1s[rr][k], W_fc1[u*HID + k], acc);
        part[0][rr][u] = fmaxf(acc, 0.f);
    }
    __syncthreads();
    if (tid < BB) {
        float acc = b_fc2[0];
        #pragma unroll 8
        for (int u = 0; u < 64; ++u) acc = fmaf(part[0][tid][u], W_fc2[u], acc);
        out[row0 + tid] = acc;
    }
}

extern "C" void kernel_launch(void* const* d_in, const int* in_sizes, int n_in,
                              void* d_out, int out_size, void* d_ws, size_t ws_size,
                              hipStream_t stream)
{
    const float* x     = (const float*)d_in[0];
    const float* W_emb = (const float*)d_in[1];
    const float* b_emb = (const float*)d_in[2];
    const float* W_ih0 = (const float*)d_in[3];
    const float* W_hh0 = (const float*)d_in[4];
    const float* b_ih0 = (const float*)d_in[5];
    const float* b_hh0 = (const float*)d_in[6];
    const float* W_ih1 = (const float*)d_in[7];
    const float* W_hh1 = (const float*)d_in[8];
    const float* b_ih1 = (const float*)d_in[9];
    const float* b_hh1 = (const float*)d_in[10];
    const float* W_fc1 = (const float*)d_in[11];
    const float* b_fc1 = (const float*)d_in[12];
    const float* W_fc2 = (const float*)d_in[13];
    const float* b_fc2 = (const float*)d_in[14];
    float* out = (float*)d_out;

    float* out0;
    hipGetSymbolAddress((void**)&out0, HIP_SYMBOL(g_out0));

    prep_kernel<<<2, 256, 0, stream>>>(W_emb, b_emb, W_ih0, W_hh0, b_ih0, b_hh0,
                                       W_ih1, W_hh1, b_ih1, b_hh1);
    lstm_l0<<<2048 / BB, NT, 0, stream>>>(x, out0);
    lstm_l1<<<2048 / BB, NT, 0, stream>>>(out0, W_fc1, b_fc1, W_fc2, b_fc2, out);
}

// Round 10
// 7995.235 us; speedup vs baseline: 1.0004x; 1.0001x over previous
//
#include <hip/hip_runtime.h>

#define TS    576
#define HID   128
#define GT    512       // 4*HID
#define GTP   640       // padded part stride -> LDS/wg > 80KB -> 1 wg/CU -> 256-VGPR budget
#define K0    144       // 15 x (emb-folded) | 128 h0 | 1 zero pad
#define BB    8         // batch rows per block
#define NT    512       // 8 waves -> 2 waves/SIMD (1 wg/CU via LDS)
#define TS128 (TS*HID)  // 73728

// prepped weights (k-major, gate-interleaved columns jn = unit*4 + gate)
__device__ float g_wt0[K0 * GT];     // [k][col]: k 0..14 x-proj (emb folded), 15..142 h, 143 zero
__device__ float g_b0[GT];
__device__ float g_wih1[HID * GT];   // [k][col]
__device__ float g_whh1[HID * GT];   // [k][col]
__device__ float g_b1[GT];
__device__ float g_out0[2048 * TS * HID];   // 604 MB intermediate: out0[b][t][128]

__global__ void prep_kernel(const float* __restrict__ W_emb, const float* __restrict__ b_emb,
                            const float* __restrict__ W_ih0, const float* __restrict__ W_hh0,
                            const float* __restrict__ b_ih0, const float* __restrict__ b_hh0,
                            const float* __restrict__ W_ih1, const float* __restrict__ W_hh1,
                            const float* __restrict__ b_ih1, const float* __restrict__ b_hh1)
{
    const int jo = blockIdx.x * blockDim.x + threadIdx.x;
    if (jo >= GT) return;
    const int g  = jo >> 7;         // gate 0..3 (i,f,g,o)
    const int u  = jo & 127;        // unit
    const int jn = (u << 2) | g;    // interleaved column

    // L0: fold embedding into x-projection
    for (int i = 0; i < 15; ++i) {
        float s = 0.f;
        for (int c = 0; c < 32; ++c) s = fmaf(W_ih0[jo*32 + c], W_emb[c*15 + i], s);
        g_wt0[i*GT + jn] = s;
    }
    for (int k = 0; k < HID; ++k) g_wt0[(15 + k)*GT + jn] = W_hh0[jo*HID + k];
    g_wt0[143*GT + jn] = 0.f;
    float bb = b_ih0[jo] + b_hh0[jo];
    for (int c = 0; c < 32; ++c) bb = fmaf(W_ih0[jo*32 + c], b_emb[c], bb);
    g_b0[jn] = bb;

    for (int k = 0; k < HID; ++k) g_wih1[k*GT + jn] = W_ih1[jo*HID + k];
    for (int k = 0; k < HID; ++k) g_whh1[k*GT + jn] = W_hh1[jo*HID + k];
    g_b1[jn] = b_ih1[jo] + b_hh1[jo];
}

__device__ __forceinline__ float sigm(float v) { return 1.f / (1.f + __expf(-v)); }

#define LD4(P_) (*(const float4*)(P_))
// macro params must never be named x/y/z/w/a/s
#define FMARC(A_, SV_, W_) \
    A_.x = fmaf(SV_, W_.x, A_.x); A_.y = fmaf(SV_, W_.y, A_.y); \
    A_.z = fmaf(SV_, W_.z, A_.z); A_.w = fmaf(SV_, W_.w, A_.w);

// ============================ Kernel A: layer-0 ============================
// LDS 86.5KB > 81.9KB -> only 1 wg/CU fits -> LDS-derived occupancy 2 waves/EU
// -> RA VGPR budget 256 -> the 144 weight VGPRs stay resident (r5/r6: 76KB LDS
// allowed 2 wg/CU -> budget pinned 128 -> weights rematerialized from L2).
__global__ void __attribute__((amdgpu_flat_work_group_size(NT, NT), amdgpu_waves_per_eu(2, 2)))
lstm_l0(const float* __restrict__ x, float* __restrict__ out0)
{
    __shared__ float src0[BB][K0];      // [15 x | 128 h0 | 1 pad]  4.6 KB
    __shared__ float part[4][BB][GTP];  // 4-way k-split partials    80 KB

    const int tid  = threadIdx.x;
    const int cg   = tid & 127;
    const int q4   = cg << 2;
    const int ks   = tid >> 7;          // 0..3, wave-uniform
    const int um   = cg;                // update unit
    const int rlo  = tid >> 7;          // update rows rlo and rlo+4
    const int row0 = blockIdx.x * BB;
    const int k0b  = ks * 36;

    // persistent weights: 36 named float4 (144 VGPRs)
    const float* p0 = g_wt0 + (size_t)k0b * GT + q4;
#define DECLA(I_) const float4 wa##I_ = LD4(p0 + (I_)*GT);
    DECLA(0)  DECLA(1)  DECLA(2)  DECLA(3)  DECLA(4)  DECLA(5)
    DECLA(6)  DECLA(7)  DECLA(8)  DECLA(9)  DECLA(10) DECLA(11)
    DECLA(12) DECLA(13) DECLA(14) DECLA(15) DECLA(16) DECLA(17)
    DECLA(18) DECLA(19) DECLA(20) DECLA(21) DECLA(22) DECLA(23)
    DECLA(24) DECLA(25) DECLA(26) DECLA(27) DECLA(28) DECLA(29)
    DECLA(30) DECLA(31) DECLA(32) DECLA(33) DECLA(34) DECLA(35)

    const float4 zz = make_float4(0.f, 0.f, 0.f, 0.f);
    const float4 i0 = (ks == 0) ? LD4(g_b0 + q4) : zz;
    float c_a = 0.f, c_b = 0.f;

    for (int i = tid; i < BB*K0; i += NT) (&src0[0][0])[i] = 0.f;

    const int lr = tid / 15, li = tid - lr * 15;
    const float* xp = x + (size_t)(row0 + (tid < 120 ? lr : 0)) * (TS * 15) + (tid < 120 ? li : 0);

    __syncthreads();
    if (tid < 120) src0[lr][li] = xp[0];
    __syncthreads();

    float* pp = &part[ks][0][0];

#define L0R(R_) { \
    const float* sp_ = &src0[R_][k0b]; \
    const float4 s0_ = LD4(sp_+0),  s1_ = LD4(sp_+4),  s2_ = LD4(sp_+8); \
    const float4 s3_ = LD4(sp_+12), s4_ = LD4(sp_+16), s5_ = LD4(sp_+20); \
    const float4 s6_ = LD4(sp_+24), s7_ = LD4(sp_+28), s8_ = LD4(sp_+32); \
    float4 acc_ = i0; \
    FMARC(acc_, s0_.x, wa0)  FMARC(acc_, s0_.y, wa1)  FMARC(acc_, s0_.z, wa2)  FMARC(acc_, s0_.w, wa3)  \
    FMARC(acc_, s1_.x, wa4)  FMARC(acc_, s1_.y, wa5)  FMARC(acc_, s1_.z, wa6)  FMARC(acc_, s1_.w, wa7)  \
    FMARC(acc_, s2_.x, wa8)  FMARC(acc_, s2_.y, wa9)  FMARC(acc_, s2_.z, wa10) FMARC(acc_, s2_.w, wa11) \
    FMARC(acc_, s3_.x, wa12) FMARC(acc_, s3_.y, wa13) FMARC(acc_, s3_.z, wa14) FMARC(acc_, s3_.w, wa15) \
    FMARC(acc_, s4_.x, wa16) FMARC(acc_, s4_.y, wa17) FMARC(acc_, s4_.z, wa18) FMARC(acc_, s4_.w, wa19) \
    FMARC(acc_, s5_.x, wa20) FMARC(acc_, s5_.y, wa21) FMARC(acc_, s5_.z, wa22) FMARC(acc_, s5_.w, wa23) \
    FMARC(acc_, s6_.x, wa24) FMARC(acc_, s6_.y, wa25) FMARC(acc_, s6_.z, wa26) FMARC(acc_, s6_.w, wa27) \
    FMARC(acc_, s7_.x, wa28) FMARC(acc_, s7_.y, wa29) FMARC(acc_, s7_.z, wa30) FMARC(acc_, s7_.w, wa31) \
    FMARC(acc_, s8_.x, wa32) FMARC(acc_, s8_.y, wa33) FMARC(acc_, s8_.z, wa34) FMARC(acc_, s8_.w, wa35) \
    *(float4*)(pp + (R_)*GTP + q4) = acc_; }

#define UPD0(R_, C_) { \
    const int ub_ = um << 2; \
    float4 gv_ = LD4(&part[0][R_][ub_]); \
    { const float4 p1_ = LD4(&part[1][R_][ub_]); gv_.x += p1_.x; gv_.y += p1_.y; gv_.z += p1_.z; gv_.w += p1_.w; } \
    { const float4 p2_ = LD4(&part[2][R_][ub_]); gv_.x += p2_.x; gv_.y += p2_.y; gv_.z += p2_.z; gv_.w += p2_.w; } \
    { const float4 p3_ = LD4(&part[3][R_][ub_]); gv_.x += p3_.x; gv_.y += p3_.y; gv_.z += p3_.z; gv_.w += p3_.w; } \
    const float iv_ = sigm(gv_.x), fv_ = sigm(gv_.y), ov_ = sigm(gv_.w); \
    const float gg_ = tanhf(gv_.z); \
    C_ = fmaf(fv_, C_, iv_ * gg_); \
    const float hv_ = ov_ * tanhf(C_); \
    src0[R_][15 + um] = hv_; \
    out0[(size_t)(row0 + (R_)) * TS128 + (size_t)t * HID + um] = hv_; }

    #pragma unroll 1
    for (int t = 0; t < TS; ++t) {
        float xnext = 0.f;
        if (tid < 120 && t + 1 < TS) xnext = xp[(size_t)(t + 1) * 15];
        L0R(0) L0R(1) L0R(2) L0R(3) L0R(4) L0R(5) L0R(6) L0R(7)
        __syncthreads();
        UPD0(rlo, c_a)
        { const int rhi_ = rlo + 4; UPD0(rhi_, c_b) }
        if (tid < 120 && t + 1 < TS) src0[lr][li] = xnext;
        __syncthreads();
    }
}

// ============================ Kernel C: layer-1 + FC head ============================
// LDS 94.2KB -> 1 wg/CU -> 256-VGPR budget (same mechanism as lstm_l0).
__global__ void __attribute__((amdgpu_flat_work_group_size(NT, NT), amdgpu_waves_per_eu(2, 2)))
lstm_l1(const float* __restrict__ out0,
        const float* __restrict__ W_fc1, const float* __restrict__ b_fc1,
        const float* __restrict__ W_fc2, const float* __restrict__ b_fc2,
        float* __restrict__ out)
{
    __shared__ float h1s[BB][HID];       // h1 state              4 KB
    __shared__ float obuf[2][BB][HID];   // out0[t] double buffer 8 KB
    __shared__ float part[4][BB][GTP];   // k-split partials     80 KB

    const int tid  = threadIdx.x;
    const int cg   = tid & 127;
    const int q4   = cg << 2;
    const int ks   = tid >> 7;
    const int um   = cg;
    const int rlo  = tid >> 7;
    const int row0 = blockIdx.x * BB;
    const int k1b  = ks * 32;

    // persistent W_hh1 slice: 32 named float4 (128 VGPRs)
    const float* ph = g_whh1 + (size_t)k1b * GT + q4;
#define DECLB(I_) const float4 wb##I_ = LD4(ph + (I_)*GT);
    DECLB(0)  DECLB(1)  DECLB(2)  DECLB(3)  DECLB(4)  DECLB(5)  DECLB(6)  DECLB(7)
    DECLB(8)  DECLB(9)  DECLB(10) DECLB(11) DECLB(12) DECLB(13) DECLB(14) DECLB(15)
    DECLB(16) DECLB(17) DECLB(18) DECLB(19) DECLB(20) DECLB(21) DECLB(22) DECLB(23)
    DECLB(24) DECLB(25) DECLB(26) DECLB(27) DECLB(28) DECLB(29) DECLB(30) DECLB(31)

    const float* pih = g_wih1 + (size_t)k1b * GT + q4;   // streamed per step (L2-resident)

    const float4 zz = make_float4(0.f, 0.f, 0.f, 0.f);
    const float4 i1 = (ks == 0) ? LD4(g_b1 + q4) : zz;
    float c_a = 0.f, c_b = 0.f;

    for (int i = tid; i < BB*HID; i += NT) (&h1s[0][0])[i] = 0.f;

    const int pr = tid >> 5, pk4 = (tid & 31) << 2;   // prefetch role (tid<256)
    float4 pf = zz;
    if (tid < 256) pf = LD4(out0 + (size_t)(row0 + pr) * TS128 + pk4);
    __syncthreads();
    if (tid < 256) *(float4*)(&obuf[0][pr][pk4]) = pf;
    __syncthreads();

    float* pp = &part[ks][0][0];

// stream-load 4 consecutive k-rows of W_ih1 into named regs
#define SWL(P_, J_) \
    P_##0 = LD4(pih + (size_t)(4*(J_)+0)*GT); \
    P_##1 = LD4(pih + (size_t)(4*(J_)+1)*GT); \
    P_##2 = LD4(pih + (size_t)(4*(J_)+2)*GT); \
    P_##3 = LD4(pih + (size_t)(4*(J_)+3)*GT);

// hh 4 k x 4 rows (RB_..RB_+3), accs AA_..AD_
#define HH4(J_, W0_, W1_, W2_, W3_, RB_, AA_, AB_, AC_, AD_) { \
    const float4 hA_ = LD4(&h1s[(RB_)+0][k1b + 4*(J_)]); \
    const float4 hB_ = LD4(&h1s[(RB_)+1][k1b + 4*(J_)]); \
    const float4 hC_ = LD4(&h1s[(RB_)+2][k1b + 4*(J_)]); \
    const float4 hD_ = LD4(&h1s[(RB_)+3][k1b + 4*(J_)]); \
    FMARC(AA_, hA_.x, W0_) FMARC(AA_, hA_.y, W1_) FMARC(AA_, hA_.z, W2_) FMARC(AA_, hA_.w, W3_) \
    FMARC(AB_, hB_.x, W0_) FMARC(AB_, hB_.y, W1_) FMARC(AB_, hB_.z, W2_) FMARC(AB_, hB_.w, W3_) \
    FMARC(AC_, hC_.x, W0_) FMARC(AC_, hC_.y, W1_) FMARC(AC_, hC_.z, W2_) FMARC(AC_, hC_.w, W3_) \
    FMARC(AD_, hD_.x, W0_) FMARC(AD_, hD_.y, W1_) FMARC(AD_, hD_.z, W2_) FMARC(AD_, hD_.w, W3_) }
#define HH(J_, W0_, W1_, W2_, W3_) \
    HH4(J_, W0_, W1_, W2_, W3_, 0, acc0, acc1, acc2, acc3) \
    HH4(J_, W0_, W1_, W2_, W3_, 4, acc4, acc5, acc6, acc7)

// ih 4 k (streamed regs P_##0..3) x 4 rows from obuf[t&1]
#define IH4(P_, J_, RB_, AA_, AB_, AC_, AD_) { \
    const float4 oA_ = LD4(ob + ((RB_)+0)*HID + k1b + 4*(J_)); \
    const float4 oB_ = LD4(ob + ((RB_)+1)*HID + k1b + 4*(J_)); \
    const float4 oC_ = LD4(ob + ((RB_)+2)*HID + k1b + 4*(J_)); \
    const float4 oD_ = LD4(ob + ((RB_)+3)*HID + k1b + 4*(J_)); \
    FMARC(AA_, oA_.x, P_##0) FMARC(AA_, oA_.y, P_##1) FMARC(AA_, oA_.z, P_##2) FMARC(AA_, oA_.w, P_##3) \
    FMARC(AB_, oB_.x, P_##0) FMARC(AB_, oB_.y, P_##1) FMARC(AB_, oB_.z, P_##2) FMARC(AB_, oB_.w, P_##3) \
    FMARC(AC_, oC_.x, P_##0) FMARC(AC_, oC_.y, P_##1) FMARC(AC_, oC_.z, P_##2) FMARC(AC_, oC_.w, P_##3) \
    FMARC(AD_, oD_.x, P_##0) FMARC(AD_, oD_.y, P_##1) FMARC(AD_, oD_.z, P_##2) FMARC(AD_, oD_.w, P_##3) }
#define IH(P_, J_) \
    IH4(P_, J_, 0, acc0, acc1, acc2, acc3) \
    IH4(P_, J_, 4, acc4, acc5, acc6, acc7)

#define UPD1(R_, C_) { \
    const int ub_ = um << 2; \
    float4 gv_ = LD4(&part[0][R_][ub_]); \
    { const float4 p1_ = LD4(&part[1][R_][ub_]); gv_.x += p1_.x; gv_.y += p1_.y; gv_.z += p1_.z; gv_.w += p1_.w; } \
    { const float4 p2_ = LD4(&part[2][R_][ub_]); gv_.x += p2_.x; gv_.y += p2_.y; gv_.z += p2_.z; gv_.w += p2_.w; } \
    { const float4 p3_ = LD4(&part[3][R_][ub_]); gv_.x += p3_.x; gv_.y += p3_.y; gv_.z += p3_.z; gv_.w += p3_.w; } \
    const float iv_ = sigm(gv_.x), fv_ = sigm(gv_.y), ov_ = sigm(gv_.w); \
    const float gg_ = tanhf(gv_.z); \
    C_ = fmaf(fv_, C_, iv_ * gg_); \
    h1s[R_][um] = ov_ * tanhf(C_); }

    #pragma unroll 1
    for (int t = 0; t < TS; ++t) {
        if (tid < 256 && t + 1 < TS)
            pf = LD4(out0 + (size_t)(row0 + pr) * TS128 + (size_t)(t + 1) * HID + pk4);

        const float* ob = &obuf[t & 1][0][0];
        float4 acc0 = i1, acc1 = i1, acc2 = i1, acc3 = i1;
        float4 acc4 = i1, acc5 = i1, acc6 = i1, acc7 = i1;
        float4 sa0, sa1, sa2, sa3, sb0, sb1, sb2, sb3;

        SWL(sa, 0) SWL(sb, 1)                  // stream chunks 0,1 in flight under hh-part
        HH(0, wb0,  wb1,  wb2,  wb3)
        HH(1, wb4,  wb5,  wb6,  wb7)
        HH(2, wb8,  wb9,  wb10, wb11)
        HH(3, wb12, wb13, wb14, wb15)
        HH(4, wb16, wb17, wb18, wb19)
        HH(5, wb20, wb21, wb22, wb23)
        HH(6, wb24, wb25, wb26, wb27)
        HH(7, wb28, wb29, wb30, wb31)
        IH(sa, 0) SWL(sa, 2)
        IH(sb, 1) SWL(sb, 3)
        IH(sa, 2) SWL(sa, 4)
        IH(sb, 3) SWL(sb, 5)
        IH(sa, 4) SWL(sa, 6)
        IH(sb, 5) SWL(sb, 7)
        IH(sa, 6)
        IH(sb, 7)

        *(float4*)(pp + 0*GTP + q4) = acc0;
        *(float4*)(pp + 1*GTP + q4) = acc1;
        *(float4*)(pp + 2*GTP + q4) = acc2;
        *(float4*)(pp + 3*GTP + q4) = acc3;
        *(float4*)(pp + 4*GTP + q4) = acc4;
        *(float4*)(pp + 5*GTP + q4) = acc5;
        *(float4*)(pp + 6*GTP + q4) = acc6;
        *(float4*)(pp + 7*GTP + q4) = acc7;
        __syncthreads();

        UPD1(rlo, c_a)
        { const int rhi_ = rlo + 4; UPD1(rhi_, c_b) }
        if (tid < 256 && t + 1 < TS) *(float4*)(&obuf[(t + 1) & 1][pr][pk4]) = pf;
        __syncthreads();
    }

    // ---- FC head: relu(h1 @ W_fc1^T + b_fc1) @ W_fc2^T + b_fc2 ----
    {
        const int rr = tid >> 6, u = tid & 63;   // 8 rows x 64 units = 512 threads
        float acc = b_fc1[u];
        #pragma unroll 8
        for (int k = 0; k < HID; ++k) acc = fmaf(h1s[rr][k], W_fc1[u*HID + k], acc);
        part[0][rr][u] = fmaxf(acc, 0.f);
    }
    __syncthreads();
    if (tid < BB) {
        float acc = b_fc2[0];
        #pragma unroll 8
        for (int u = 0; u < 64; ++u) acc = fmaf(part[0][tid][u], W_fc2[u], acc);
        out[row0 + tid] = acc;
    }
}

extern "C" void kernel_launch(void* const* d_in, const int* in_sizes, int n_in,
                              void* d_out, int out_size, void* d_ws, size_t ws_size,
                              hipStream_t stream)
{
    const float* x     = (const float*)d_in[0];
    const float* W_emb = (const float*)d_in[1];
    const float* b_emb = (const float*)d_in[2];
    const float* W_ih0 = (const float*)d_in[3];
    const float* W_hh0 = (const float*)d_in[4];
    const float* b_ih0 = (const float*)d_in[5];
    const float* b_hh0 = (const float*)d_in[6];
    const float* W_ih1 = (const float*)d_in[7];
    const float* W_hh1 = (const float*)d_in[8];
    const float* b_ih1 = (const float*)d_in[9];
    const float* b_hh1 = (const float*)d_in[10];
    const float* W_fc1 = (const float*)d_in[11];
    const float* b_fc1 = (const float*)d_in[12];
    const float* W_fc2 = (const float*)d_in[13];
    const float* b_fc2 = (const float*)d_in[14];
    float* out = (float*)d_out;

    float* out0;
    hipGetSymbolAddress((void**)&out0, HIP_SYMBOL(g_out0));

    prep_kernel<<<2, 256, 0, stream>>>(W_emb, b_emb, W_ih0, W_hh0, b_ih0, b_hh0,
                                       W_ih1, W_hh1, b_ih1, b_hh1);
    lstm_l0<<<2048 / BB, NT, 0, stream>>>(x, out0);
    lstm_l1<<<2048 / BB, NT, 0, stream>>>(out0, W_fc1, b_fc1, W_fc2, b_fc2, out);
}

// Round 11
// 6712.183 us; speedup vs baseline: 1.1916x; 1.1912x over previous
//
#include <hip/hip_runtime.h>

#define TS    576
#define TC    144          // timesteps per l1/proj chunk (4 chunks)
#define HID   128
#define GT    512          // 4*HID
#define K0P   160          // 15 x (emb-folded) | 128 h0 | 17 zero pad
#define BB    8            // batch rows per block
#define NT    1024         // lstm kernels: 16 waves, 1 wg/CU (LDS-forced)
#define BNT   256          // proj kernel threads
#define BROWS 32           // proj rows per block
#define TS128 (TS*HID)

// prepped weights (k-major, gate-interleaved columns jn = unit*4 + gate)
__device__ float g_wt0[K0P * GT];
__device__ float g_b0[GT];
__device__ float g_wih1[HID * GT];
__device__ float g_whh1[HID * GT];
__device__ float g_b1[GT];
__device__ float g_out0[(size_t)2048 * TS * HID];   // 604 MB
__device__ float g_G1[(size_t)2048 * TC * GT];      // 604 MB: G1 chunk [b*TC+tc][512]
__device__ float g_h1[2048 * HID];                  // l1 h state across chunks
__device__ float g_c1[2048 * HID];                  // l1 c state across chunks

__global__ void prep_kernel(const float* __restrict__ W_emb, const float* __restrict__ b_emb,
                            const float* __restrict__ W_ih0, const float* __restrict__ W_hh0,
                            const float* __restrict__ b_ih0, const float* __restrict__ b_hh0,
                            const float* __restrict__ W_ih1, const float* __restrict__ W_hh1,
                            const float* __restrict__ b_ih1, const float* __restrict__ b_hh1)
{
    const int jo = blockIdx.x * blockDim.x + threadIdx.x;
    if (jo >= GT) return;
    const int g  = jo >> 7;         // gate 0..3 (i,f,g,o)
    const int u  = jo & 127;        // unit
    const int jn = (u << 2) | g;    // interleaved column

    for (int i = 0; i < 15; ++i) {
        float s = 0.f;
        for (int c = 0; c < 32; ++c) s = fmaf(W_ih0[jo*32 + c], W_emb[c*15 + i], s);
        g_wt0[i*GT + jn] = s;
    }
    for (int k = 0; k < HID; ++k) g_wt0[(15 + k)*GT + jn] = W_hh0[jo*HID + k];
    for (int k = 143; k < K0P; ++k) g_wt0[k*GT + jn] = 0.f;
    float bb = b_ih0[jo] + b_hh0[jo];
    for (int c = 0; c < 32; ++c) bb = fmaf(W_ih0[jo*32 + c], b_emb[c], bb);
    g_b0[jn] = bb;

    for (int k = 0; k < HID; ++k) g_wih1[k*GT + jn] = W_ih1[jo*HID + k];
    for (int k = 0; k < HID; ++k) g_whh1[k*GT + jn] = W_hh1[jo*HID + k];
    g_b1[jn] = b_ih1[jo] + b_hh1[jo];
}

__device__ __forceinline__ float sigm(float v) { return 1.f / (1.f + __expf(-v)); }

#define LD4(P_) (*(const float4*)(P_))
// macro params must never be named x/y/z/w/a/s
#define FMARC(A_, SV_, W_) \
    A_.x = fmaf(SV_, W_.x, A_.x); A_.y = fmaf(SV_, W_.y, A_.y); \
    A_.z = fmaf(SV_, W_.z, A_.z); A_.w = fmaf(SV_, W_.w, A_.w);

// ============================ Kernel A: layer-0 ============================
// NT=1024, 8-way k-split -> 20 float4 weight regs/thread: fits the 128-VGPR
// budget the allocator enforces at 4 waves/EU (r4-r10 evidence: attributes
// cannot raise it past 128; so fit inside it instead).
__global__ void __attribute__((amdgpu_flat_work_group_size(NT, NT)))
lstm_l0(const float* __restrict__ x, float* __restrict__ out0)
{
    __shared__ float src0[BB][K0P];     // 5 KB
    __shared__ float part[8][BB][GT];   // 128 KB -> 1 wg/CU

    const int tid  = threadIdx.x;
    const int cg   = tid & 127;
    const int q4   = cg << 2;
    const int ks   = tid >> 7;          // 0..7, wave-uniform
    const int um   = cg;                // update: unit
    const int ur   = tid >> 7;          // update: row
    const int row0 = blockIdx.x * BB;
    const int k0b  = ks * 20;

    const float* p0 = g_wt0 + (size_t)k0b * GT + q4;
#define DECLA(I_) const float4 wa##I_ = LD4(p0 + (I_)*GT);
    DECLA(0)  DECLA(1)  DECLA(2)  DECLA(3)  DECLA(4)
    DECLA(5)  DECLA(6)  DECLA(7)  DECLA(8)  DECLA(9)
    DECLA(10) DECLA(11) DECLA(12) DECLA(13) DECLA(14)
    DECLA(15) DECLA(16) DECLA(17) DECLA(18) DECLA(19)

    const float4 zz = make_float4(0.f, 0.f, 0.f, 0.f);
    const float4 i0 = (ks == 0) ? LD4(g_b0 + q4) : zz;
    float c0 = 0.f;

    for (int i = tid; i < BB*K0P; i += NT) (&src0[0][0])[i] = 0.f;

    const int lr = tid / 15, li = tid - lr * 15;
    const float* xp = x + (size_t)(row0 + (tid < 120 ? lr : 0)) * (TS * 15) + (tid < 120 ? li : 0);

    __syncthreads();
    if (tid < 120) src0[lr][li] = xp[0];
    __syncthreads();

    float* pp = &part[ks][0][0];

#define L0R(R_) { \
    const float* sp_ = &src0[R_][k0b]; \
    const float4 s0_ = LD4(sp_+0),  s1_ = LD4(sp_+4),  s2_ = LD4(sp_+8); \
    const float4 s3_ = LD4(sp_+12), s4_ = LD4(sp_+16); \
    float4 acc_ = i0; \
    FMARC(acc_, s0_.x, wa0)  FMARC(acc_, s0_.y, wa1)  FMARC(acc_, s0_.z, wa2)  FMARC(acc_, s0_.w, wa3)  \
    FMARC(acc_, s1_.x, wa4)  FMARC(acc_, s1_.y, wa5)  FMARC(acc_, s1_.z, wa6)  FMARC(acc_, s1_.w, wa7)  \
    FMARC(acc_, s2_.x, wa8)  FMARC(acc_, s2_.y, wa9)  FMARC(acc_, s2_.z, wa10) FMARC(acc_, s2_.w, wa11) \
    FMARC(acc_, s3_.x, wa12) FMARC(acc_, s3_.y, wa13) FMARC(acc_, s3_.z, wa14) FMARC(acc_, s3_.w, wa15) \
    FMARC(acc_, s4_.x, wa16) FMARC(acc_, s4_.y, wa17) FMARC(acc_, s4_.z, wa18) FMARC(acc_, s4_.w, wa19) \
    *(float4*)(pp + (R_)*GT + q4) = acc_; }

    #pragma unroll 1
    for (int t = 0; t < TS; ++t) {
        float xnext = 0.f;
        if (tid < 120 && t + 1 < TS) xnext = xp[(size_t)(t + 1) * 15];
        L0R(0) L0R(1) L0R(2) L0R(3) L0R(4) L0R(5) L0R(6) L0R(7)
        __syncthreads();
        {
            const int ub = um << 2;
            float4 gv = LD4(&part[0][ur][ub]);
            #pragma unroll
            for (int s = 1; s < 8; ++s) {
                const float4 p = LD4(&part[s][ur][ub]);
                gv.x += p.x; gv.y += p.y; gv.z += p.z; gv.w += p.w;
            }
            const float iv = sigm(gv.x), fv = sigm(gv.y), ov = sigm(gv.w);
            const float gg = tanhf(gv.z);
            c0 = fmaf(fv, c0, iv * gg);
            const float hv = ov * tanhf(c0);
            src0[ur][15 + um] = hv;
            out0[(size_t)(row0 + ur) * TS128 + (size_t)t * HID + um] = hv;
        }
        if (tid < 120 && t + 1 < TS) src0[lr][li] = xnext;
        __syncthreads();
    }
}

// ============== Kernel B: parallel projection G1 = out0 @ W_ih1^T + b1 ==============
// One time-chunk of TC steps; rows are chunk-flat r = b*TC + tc.
__global__ void __launch_bounds__(BNT)
proj1(int t0)
{
    __shared__ float At[HID][36];   // A-tile transposed [k][row], pad 36 (16B-aligned reads)

    const int tid = threadIdx.x;
    const int rb  = blockIdx.x * BROWS;

    // load 32 rows x 128 k, store transposed
    {
        const int row = tid >> 3;
        const int g   = rb + row;
        const int b   = g / TC;
        const int tc  = g - b * TC;
        const float* src = g_out0 + (size_t)(b * TS + t0 + tc) * HID;
        #pragma unroll
        for (int i = 0; i < 4; ++i) {
            const int kq = (tid & 7) + 8 * i;
            const float4 v = LD4(src + kq * 4);
            At[kq*4 + 0][row] = v.x;
            At[kq*4 + 1][row] = v.y;
            At[kq*4 + 2][row] = v.z;
            At[kq*4 + 3][row] = v.w;
        }
    }
    __syncthreads();

    const int q  = tid & 127;        // col quad
    const int r0 = (tid >> 7) * 16;  // row base (0 or 16)
    const float4 bq = LD4(g_b1 + q * 4);
    float4 a0=bq,a1=bq,a2=bq,a3=bq,a4=bq,a5=bq,a6=bq,a7=bq;
    float4 a8=bq,a9=bq,a10=bq,a11=bq,a12=bq,a13=bq,a14=bq,a15=bq;

    const float* wp = g_wih1 + q * 4;
    #pragma unroll 4
    for (int k = 0; k < HID; ++k) {
        const float4 wv = LD4(wp + (size_t)k * GT);
        const float4 h0_ = LD4(&At[k][r0 + 0]);
        const float4 h1_ = LD4(&At[k][r0 + 4]);
        const float4 h2_ = LD4(&At[k][r0 + 8]);
        const float4 h3_ = LD4(&At[k][r0 + 12]);
        FMARC(a0,  h0_.x, wv) FMARC(a1,  h0_.y, wv) FMARC(a2,  h0_.z, wv) FMARC(a3,  h0_.w, wv)
        FMARC(a4,  h1_.x, wv) FMARC(a5,  h1_.y, wv) FMARC(a6,  h1_.z, wv) FMARC(a7,  h1_.w, wv)
        FMARC(a8,  h2_.x, wv) FMARC(a9,  h2_.y, wv) FMARC(a10, h2_.z, wv) FMARC(a11, h2_.w, wv)
        FMARC(a12, h3_.x, wv) FMARC(a13, h3_.y, wv) FMARC(a14, h3_.z, wv) FMARC(a15, h3_.w, wv)
    }

    float* dst = g_G1 + (size_t)(rb + r0) * GT + q * 4;
#define STG(I_) *(float4*)(dst + (size_t)(I_) * GT) = a##I_;
    STG(0) STG(1) STG(2) STG(3) STG(4) STG(5) STG(6) STG(7)
    STG(8) STG(9) STG(10) STG(11) STG(12) STG(13) STG(14) STG(15)
}

// ============== Kernel C: recurrent layer-1 (W_hh1 only) + FC head ==============
__global__ void __attribute__((amdgpu_flat_work_group_size(NT, NT)))
lstm_l1(int t0, int last,
        const float* __restrict__ W_fc1, const float* __restrict__ b_fc1,
        const float* __restrict__ W_fc2, const float* __restrict__ b_fc2,
        float* __restrict__ out)
{
    __shared__ float h1s[BB][HID];      //   4 KB
    __shared__ float obuf[BB][GT];      //  16 KB: G1[t] slab
    __shared__ float part[8][BB][GT];   // 128 KB -> 1 wg/CU (total 148 KB)

    const int tid  = threadIdx.x;
    const int cg   = tid & 127;
    const int q4   = cg << 2;
    const int ks   = tid >> 7;          // 0..7
    const int um   = cg;
    const int ur   = tid >> 7;
    const int row0 = blockIdx.x * BB;
    const int k1b  = ks * 16;

    // persistent W_hh1 slice: 16 named float4 (64 VGPRs) — fits 128 budget
    const float* ph = g_whh1 + (size_t)k1b * GT + q4;
#define DECLB(I_) const float4 wb##I_ = LD4(ph + (I_)*GT);
    DECLB(0)  DECLB(1)  DECLB(2)  DECLB(3)
    DECLB(4)  DECLB(5)  DECLB(6)  DECLB(7)
    DECLB(8)  DECLB(9)  DECLB(10) DECLB(11)
    DECLB(12) DECLB(13) DECLB(14) DECLB(15)

    const float4 zz = make_float4(0.f, 0.f, 0.f, 0.f);
    float c1;

    // state init / restore (chunk 0 re-derives from zero -> deterministic)
    if (t0 == 0) {
        h1s[ur][um] = 0.f;
        c1 = 0.f;
    } else {
        h1s[ur][um] = g_h1[(row0 + ur) * HID + um];
        c1 = g_c1[(row0 + ur) * HID + um];
    }

    // initial G1 slab: each thread one float4
    const int pr = tid >> 7, pq = tid & 127;
    const float* gp = g_G1 + ((size_t)(row0 + pr) * TC) * GT + pq * 4;
    float4 pf = LD4(gp);
    __syncthreads();
    *(float4*)(&obuf[pr][pq << 2]) = pf;
    __syncthreads();

    float* pp = &part[ks][0][0];

#define L1R(R_) { \
    const float4 h0_ = LD4(&h1s[R_][k1b + 0]); \
    const float4 h1_ = LD4(&h1s[R_][k1b + 4]); \
    const float4 h2_ = LD4(&h1s[R_][k1b + 8]); \
    const float4 h3_ = LD4(&h1s[R_][k1b + 12]); \
    float4 acc_ = (ks == 0) ? LD4(&obuf[R_][q4]) : zz; \
    FMARC(acc_, h0_.x, wb0)  FMARC(acc_, h0_.y, wb1)  FMARC(acc_, h0_.z, wb2)  FMARC(acc_, h0_.w, wb3)  \
    FMARC(acc_, h1_.x, wb4)  FMARC(acc_, h1_.y, wb5)  FMARC(acc_, h1_.z, wb6)  FMARC(acc_, h1_.w, wb7)  \
    FMARC(acc_, h2_.x, wb8)  FMARC(acc_, h2_.y, wb9)  FMARC(acc_, h2_.z, wb10) FMARC(acc_, h2_.w, wb11) \
    FMARC(acc_, h3_.x, wb12) FMARC(acc_, h3_.y, wb13) FMARC(acc_, h3_.z, wb14) FMARC(acc_, h3_.w, wb15) \
    *(float4*)(pp + (R_)*GT + q4) = acc_; }

    #pragma unroll 1
    for (int tc = 0; tc < TC; ++tc) {
        L1R(0) L1R(1) L1R(2) L1R(3) L1R(4) L1R(5) L1R(6) L1R(7)
        if (tc + 1 < TC) pf = LD4(gp + (size_t)(tc + 1) * GT);   // prefetch next slab
        __syncthreads();
        {
            const int ub = um << 2;
            float4 gv = LD4(&part[0][ur][ub]);
            #pragma unroll
            for (int s = 1; s < 8; ++s) {
                const float4 p = LD4(&part[s][ur][ub]);
                gv.x += p.x; gv.y += p.y; gv.z += p.z; gv.w += p.w;
            }
            const float iv = sigm(gv.x), fv = sigm(gv.y), ov = sigm(gv.w);
            const float gg = tanhf(gv.z);
            c1 = fmaf(fv, c1, iv * gg);
            h1s[ur][um] = ov * tanhf(c1);
        }
        if (tc + 1 < TC) *(float4*)(&obuf[pr][pq << 2]) = pf;
        __syncthreads();
    }

    // persist state for next chunk
    g_h1[(row0 + ur) * HID + um] = h1s[ur][um];
    g_c1[(row0 + ur) * HID + um] = c1;

    if (last) {
        // FC head: relu(h1 @ W_fc1^T + b_fc1) @ W_fc2^T + b_fc2
        if (tid < BB * 64) {
            const int rr = tid >> 6, u = tid & 63;
            float acc = b_fc1[u];
            #pragma unroll 8
            for (int k = 0; k < HID; ++k) acc = fmaf(h1s[rr][k], W_fc1[u*HID + k], acc);
            part[0][rr][u] = fmaxf(acc, 0.f);
        }
        __syncthreads();
        if (tid < BB) {
            float acc = b_fc2[0];
            #pragma unroll 8
            for (int u = 0; u < 64; ++u) acc = fmaf(part[0][tid][u], W_fc2[u], acc);
            out[row0 + tid] = acc;
        }
    }
}

extern "C" void kernel_launch(void* const* d_in, const int* in_sizes, int n_in,
                              void* d_out, int out_size, void* d_ws, size_t ws_size,
                              hipStream_t stream)
{
    const float* x     = (const float*)d_in[0];
    const float* W_emb = (const float*)d_in[1];
    const float* b_emb = (const float*)d_in[2];
    const float* W_ih0 = (const float*)d_in[3];
    const float* W_hh0 = (const float*)d_in[4];
    const float* b_ih0 = (const float*)d_in[5];
    const float* b_hh0 = (const float*)d_in[6];
    const float* W_ih1 = (const float*)d_in[7];
    const float* W_hh1 = (const float*)d_in[8];
    const float* b_ih1 = (const float*)d_in[9];
    const float* b_hh1 = (const float*)d_in[10];
    const float* W_fc1 = (const float*)d_in[11];
    const float* b_fc1 = (const float*)d_in[12];
    const float* W_fc2 = (const float*)d_in[13];
    const float* b_fc2 = (const float*)d_in[14];
    float* out = (float*)d_out;

    float* out0;
    hipGetSymbolAddress((void**)&out0, HIP_SYMBOL(g_out0));

    prep_kernel<<<2, 256, 0, stream>>>(W_emb, b_emb, W_ih0, W_hh0, b_ih0, b_hh0,
                                       W_ih1, W_hh1, b_ih1, b_hh1);
    lstm_l0<<<2048 / BB, NT, 0, stream>>>(x, out0);

    const int projBlocks = 2048 * TC / BROWS;   // 9216
    for (int c = 0; c < TS / TC; ++c) {
        proj1<<<projBlocks, BNT, 0, stream>>>(c * TC);
        lstm_l1<<<2048 / BB, NT, 0, stream>>>(c * TC, (c == TS / TC - 1) ? 1 : 0,
                                              W_fc1, b_fc1, W_fc2, b_fc2, out);
    }
}

// Round 13
// 6553.683 us; speedup vs baseline: 1.2205x; 1.0242x over previous
//
#include <hip/hip_runtime.h>

#define TS    576
#define TC    288          // timesteps per l1/proj chunk (2 chunks; keeps statics < 2 GiB)
#define HID   128
#define GT    512          // 4*HID
#define K0P   160          // 15 x (emb-folded) | 128 h0 | 17 zero pad
#define BB    8            // batch rows per block
#define NT    1024         // lstm kernels: 16 waves, 1 wg/CU (LDS-forced)
#define BNT   256          // proj kernel threads
#define BROWS 32           // proj rows per block
#define TS128 (TS*HID)

// prepped weights (k-major, gate-interleaved columns jn = unit*4 + gate)
__device__ float g_wt0[K0P * GT];
__device__ float g_b0[GT];
__device__ float g_wih1[HID * GT];
__device__ float g_whh1[HID * GT];
__device__ float g_b1[GT];
__device__ float g_out0[(size_t)2048 * TS * HID];   // 604 MB: out0[b][t][128]
__device__ float g_G1[(size_t)2048 * TC * GT];      // 1.21 GB: G1 chunk [b*TC+tc][512]
__device__ float g_h1[2048 * HID];                  // l1 h state across chunks
__device__ float g_c1[2048 * HID];                  // l1 c state across chunks

__global__ void prep_kernel(const float* __restrict__ W_emb, const float* __restrict__ b_emb,
                            const float* __restrict__ W_ih0, const float* __restrict__ W_hh0,
                            const float* __restrict__ b_ih0, const float* __restrict__ b_hh0,
                            const float* __restrict__ W_ih1, const float* __restrict__ W_hh1,
                            const float* __restrict__ b_ih1, const float* __restrict__ b_hh1)
{
    const int jo = blockIdx.x * blockDim.x + threadIdx.x;
    if (jo >= GT) return;
    const int g  = jo >> 7;         // gate 0..3 (i,f,g,o)
    const int u  = jo & 127;        // unit
    const int jn = (u << 2) | g;    // interleaved column

    for (int i = 0; i < 15; ++i) {
        float s = 0.f;
        for (int c = 0; c < 32; ++c) s = fmaf(W_ih0[jo*32 + c], W_emb[c*15 + i], s);
        g_wt0[i*GT + jn] = s;
    }
    for (int k = 0; k < HID; ++k) g_wt0[(15 + k)*GT + jn] = W_hh0[jo*HID + k];
    for (int k = 143; k < K0P; ++k) g_wt0[k*GT + jn] = 0.f;
    float bb = b_ih0[jo] + b_hh0[jo];
    for (int c = 0; c < 32; ++c) bb = fmaf(W_ih0[jo*32 + c], b_emb[c], bb);
    g_b0[jn] = bb;

    for (int k = 0; k < HID; ++k) g_wih1[k*GT + jn] = W_ih1[jo*HID + k];
    for (int k = 0; k < HID; ++k) g_whh1[k*GT + jn] = W_hh1[jo*HID + k];
    g_b1[jn] = b_ih1[jo] + b_hh1[jo];
}

// Fast activations: v_exp + v_rcp approx (err ~1e-6 << 4.66e-4 budget).
// Sits on the serial post-barrier path of every timestep.
__device__ __forceinline__ float sigm(float v)   { return __builtin_amdgcn_rcpf(1.f + __expf(-v)); }
__device__ __forceinline__ float tanh_f(float v) { return 1.f - 2.f * __builtin_amdgcn_rcpf(1.f + __expf(2.f * v)); }

#define LD4(P_) (*(const float4*)(P_))
// macro params must never be named x/y/z/w/a/s
#define FMARC(A_, SV_, W_) \
    A_.x = fmaf(SV_, W_.x, A_.x); A_.y = fmaf(SV_, W_.y, A_.y); \
    A_.z = fmaf(SV_, W_.z, A_.z); A_.w = fmaf(SV_, W_.w, A_.w);

// ============================ Kernel A: layer-0 ============================
// NT=1024, 8-way k-split, 20 float4 weight regs/thread (fits the 128-VGPR
// budget the allocator enforces at 4 waves/EU; r4-r10 evidence).
__global__ void __attribute__((amdgpu_flat_work_group_size(NT, NT)))
lstm_l0(const float* __restrict__ x, float* __restrict__ out0)
{
    __shared__ float src0[BB][K0P];     // 5 KB
    __shared__ float part[8][BB][GT];   // 128 KB -> 1 wg/CU

    const int tid  = threadIdx.x;
    const int cg   = tid & 127;
    const int q4   = cg << 2;
    const int ks   = tid >> 7;          // 0..7, wave-uniform
    const int um   = cg;                // update: unit
    const int ur   = tid >> 7;          // update: row
    const int row0 = blockIdx.x * BB;
    const int k0b  = ks * 20;

    const float* p0 = g_wt0 + (size_t)k0b * GT + q4;
#define DECLA(I_) const float4 wa##I_ = LD4(p0 + (I_)*GT);
    DECLA(0)  DECLA(1)  DECLA(2)  DECLA(3)  DECLA(4)
    DECLA(5)  DECLA(6)  DECLA(7)  DECLA(8)  DECLA(9)
    DECLA(10) DECLA(11) DECLA(12) DECLA(13) DECLA(14)
    DECLA(15) DECLA(16) DECLA(17) DECLA(18) DECLA(19)

    const float4 zz = make_float4(0.f, 0.f, 0.f, 0.f);
    const float4 i0 = (ks == 0) ? LD4(g_b0 + q4) : zz;
    float c0 = 0.f;

    for (int i = tid; i < BB*K0P; i += NT) (&src0[0][0])[i] = 0.f;

    const int lr = tid / 15, li = tid - lr * 15;
    const float* xp = x + (size_t)(row0 + (tid < 120 ? lr : 0)) * (TS * 15) + (tid < 120 ? li : 0);

    __syncthreads();
    if (tid < 120) src0[lr][li] = xp[0];
    __syncthreads();

    float* pp = &part[ks][0][0];

#define L0R(R_) { \
    const float* sp_ = &src0[R_][k0b]; \
    const float4 s0_ = LD4(sp_+0),  s1_ = LD4(sp_+4),  s2_ = LD4(sp_+8); \
    const float4 s3_ = LD4(sp_+12), s4_ = LD4(sp_+16); \
    float4 acc_ = i0; \
    FMARC(acc_, s0_.x, wa0)  FMARC(acc_, s0_.y, wa1)  FMARC(acc_, s0_.z, wa2)  FMARC(acc_, s0_.w, wa3)  \
    FMARC(acc_, s1_.x, wa4)  FMARC(acc_, s1_.y, wa5)  FMARC(acc_, s1_.z, wa6)  FMARC(acc_, s1_.w, wa7)  \
    FMARC(acc_, s2_.x, wa8)  FMARC(acc_, s2_.y, wa9)  FMARC(acc_, s2_.z, wa10) FMARC(acc_, s2_.w, wa11) \
    FMARC(acc_, s3_.x, wa12) FMARC(acc_, s3_.y, wa13) FMARC(acc_, s3_.z, wa14) FMARC(acc_, s3_.w, wa15) \
    FMARC(acc_, s4_.x, wa16) FMARC(acc_, s4_.y, wa17) FMARC(acc_, s4_.z, wa18) FMARC(acc_, s4_.w, wa19) \
    *(float4*)(pp + (R_)*GT + q4) = acc_; }

    #pragma unroll 1
    for (int t = 0; t < TS; ++t) {
        float xnext = 0.f;
        if (tid < 120 && t + 1 < TS) xnext = xp[(size_t)(t + 1) * 15];
        L0R(0) L0R(1) L0R(2) L0R(3) L0R(4) L0R(5) L0R(6) L0R(7)
        __syncthreads();
        {
            const int ub = um << 2;
            float4 gv = LD4(&part[0][ur][ub]);
            #pragma unroll
            for (int s = 1; s < 8; ++s) {
                const float4 p = LD4(&part[s][ur][ub]);
                gv.x += p.x; gv.y += p.y; gv.z += p.z; gv.w += p.w;
            }
            const float iv = sigm(gv.x), fv = sigm(gv.y), ov = sigm(gv.w);
            const float gg = tanh_f(gv.z);
            c0 = fmaf(fv, c0, iv * gg);
            const float hv = ov * tanh_f(c0);
            src0[ur][15 + um] = hv;
            out0[(size_t)(row0 + ur) * TS128 + (size_t)t * HID + um] = hv;
        }
        if (tid < 120 && t + 1 < TS) src0[lr][li] = xnext;
        __syncthreads();
    }
}

// ============== Kernel B: parallel projection G1 = out0 @ W_ih1^T + b1 ==============
// One time-chunk of TC steps; chunk-flat rows g = b*TC + tc.
__global__ void __launch_bounds__(BNT)
proj1(int t0)
{
    __shared__ float At[HID][36];   // A-tile transposed [k][row], pad 36

    const int tid = threadIdx.x;
    const int rb  = blockIdx.x * BROWS;

    {
        const int row = tid >> 3;
        const int g   = rb + row;
        const int b   = g / TC;
        const int tc  = g - b * TC;
        const float* src = g_out0 + (size_t)(b * TS + t0 + tc) * HID;
        #pragma unroll
        for (int i = 0; i < 4; ++i) {
            const int kq = (tid & 7) + 8 * i;
            const float4 v = LD4(src + kq * 4);
            At[kq*4 + 0][row] = v.x;
            At[kq*4 + 1][row] = v.y;
            At[kq*4 + 2][row] = v.z;
            At[kq*4 + 3][row] = v.w;
        }
    }
    __syncthreads();

    const int q  = tid & 127;        // col quad
    const int r0 = (tid >> 7) * 16;  // row base (0 or 16)
    const float4 bq = LD4(g_b1 + q * 4);
    float4 a0=bq,a1=bq,a2=bq,a3=bq,a4=bq,a5=bq,a6=bq,a7=bq;
    float4 a8=bq,a9=bq,a10=bq,a11=bq,a12=bq,a13=bq,a14=bq,a15=bq;

    const float* wp = g_wih1 + q * 4;
    #pragma unroll 4
    for (int k = 0; k < HID; ++k) {
        const float4 wv = LD4(wp + (size_t)k * GT);
        const float4 h0_ = LD4(&At[k][r0 + 0]);
        const float4 h1_ = LD4(&At[k][r0 + 4]);
        const float4 h2_ = LD4(&At[k][r0 + 8]);
        const float4 h3_ = LD4(&At[k][r0 + 12]);
        FMARC(a0,  h0_.x, wv) FMARC(a1,  h0_.y, wv) FMARC(a2,  h0_.z, wv) FMARC(a3,  h0_.w, wv)
        FMARC(a4,  h1_.x, wv) FMARC(a5,  h1_.y, wv) FMARC(a6,  h1_.z, wv) FMARC(a7,  h1_.w, wv)
        FMARC(a8,  h2_.x, wv) FMARC(a9,  h2_.y, wv) FMARC(a10, h2_.z, wv) FMARC(a11, h2_.w, wv)
        FMARC(a12, h3_.x, wv) FMARC(a13, h3_.y, wv) FMARC(a14, h3_.z, wv) FMARC(a15, h3_.w, wv)
    }

    float* dst = g_G1 + (size_t)(rb + r0) * GT + q * 4;
#define STG(I_) *(float4*)(dst + (size_t)(I_) * GT) = a##I_;
    STG(0) STG(1) STG(2) STG(3) STG(4) STG(5) STG(6) STG(7)
    STG(8) STG(9) STG(10) STG(11) STG(12) STG(13) STG(14) STG(15)
}

// ============== Kernel C: recurrent layer-1 (W_hh1 only) + FC head ==============
__global__ void __attribute__((amdgpu_flat_work_group_size(NT, NT)))
lstm_l1(int t0, int last,
        const float* __restrict__ W_fc1, const float* __restrict__ b_fc1,
        const float* __restrict__ W_fc2, const float* __restrict__ b_fc2,
        float* __restrict__ out)
{
    __shared__ float h1s[BB][HID];      //   4 KB
    __shared__ float obuf[BB][GT];      //  16 KB: G1[t] slab
    __shared__ float part[8][BB][GT];   // 128 KB -> 1 wg/CU (total 148 KB)

    const int tid  = threadIdx.x;
    const int cg   = tid & 127;
    const int q4   = cg << 2;
    const int ks   = tid >> 7;          // 0..7
    const int um   = cg;
    const int ur   = tid >> 7;
    const int row0 = blockIdx.x * BB;
    const int k1b  = ks * 16;

    // persistent W_hh1 slice: 16 named float4 (64 VGPRs)
    const float* ph = g_whh1 + (size_t)k1b * GT + q4;
#define DECLB(I_) const float4 wb##I_ = LD4(ph + (I_)*GT);
    DECLB(0)  DECLB(1)  DECLB(2)  DECLB(3)
    DECLB(4)  DECLB(5)  DECLB(6)  DECLB(7)
    DECLB(8)  DECLB(9)  DECLB(10) DECLB(11)
    DECLB(12) DECLB(13) DECLB(14) DECLB(15)

    const float4 zz = make_float4(0.f, 0.f, 0.f, 0.f);
    float c1;

    // state init / restore (chunk 0 re-derives from zero -> deterministic)
    if (t0 == 0) {
        h1s[ur][um] = 0.f;
        c1 = 0.f;
    } else {
        h1s[ur][um] = g_h1[(row0 + ur) * HID + um];
        c1 = g_c1[(row0 + ur) * HID + um];
    }

    // initial G1 slab: each thread one float4
    const int pr = tid >> 7, pq = tid & 127;
    const float* gp = g_G1 + ((size_t)(row0 + pr) * TC) * GT + pq * 4;
    float4 pf = LD4(gp);
    __syncthreads();
    *(float4*)(&obuf[pr][pq << 2]) = pf;
    __syncthreads();

    float* pp = &part[ks][0][0];

#define L1R(R_) { \
    const float4 h0_ = LD4(&h1s[R_][k1b + 0]); \
    const float4 h1_ = LD4(&h1s[R_][k1b + 4]); \
    const float4 h2_ = LD4(&h1s[R_][k1b + 8]); \
    const float4 h3_ = LD4(&h1s[R_][k1b + 12]); \
    float4 acc_ = (ks == 0) ? LD4(&obuf[R_][q4]) : zz; \
    FMARC(acc_, h0_.x, wb0)  FMARC(acc_, h0_.y, wb1)  FMARC(acc_, h0_.z, wb2)  FMARC(acc_, h0_.w, wb3)  \
    FMARC(acc_, h1_.x, wb4)  FMARC(acc_, h1_.y, wb5)  FMARC(acc_, h1_.z, wb6)  FMARC(acc_, h1_.w, wb7)  \
    FMARC(acc_, h2_.x, wb8)  FMARC(acc_, h2_.y, wb9)  FMARC(acc_, h2_.z, wb10) FMARC(acc_, h2_.w, wb11) \
    FMARC(acc_, h3_.x, wb12) FMARC(acc_, h3_.y, wb13) FMARC(acc_, h3_.z, wb14) FMARC(acc_, h3_.w, wb15) \
    *(float4*)(pp + (R_)*GT + q4) = acc_; }

    #pragma unroll 1
    for (int tc = 0; tc < TC; ++tc) {
        L1R(0) L1R(1) L1R(2) L1R(3) L1R(4) L1R(5) L1R(6) L1R(7)
        if (tc + 1 < TC) pf = LD4(gp + (size_t)(tc + 1) * GT);   // prefetch next slab
        __syncthreads();
        {
            const int ub = um << 2;
            float4 gv = LD4(&part[0][ur][ub]);
            #pragma unroll
            for (int s = 1; s < 8; ++s) {
                const float4 p = LD4(&part[s][ur][ub]);
                gv.x += p.x; gv.y += p.y; gv.z += p.z; gv.w += p.w;
            }
            const float iv = sigm(gv.x), fv = sigm(gv.y), ov = sigm(gv.w);
            const float gg = tanh_f(gv.z);
            c1 = fmaf(fv, c1, iv * gg);
            h1s[ur][um] = ov * tanh_f(c1);
        }
        if (tc + 1 < TC) *(float4*)(&obuf[pr][pq << 2]) = pf;
        __syncthreads();
    }

    // persist state for next chunk
    g_h1[(row0 + ur) * HID + um] = h1s[ur][um];
    g_c1[(row0 + ur) * HID + um] = c1;

    if (last) {
        // FC head: relu(h1 @ W_fc1^T + b_fc1) @ W_fc2^T + b_fc2
        if (tid < BB * 64) {
            const int rr = tid >> 6, u = tid & 63;
            float acc = b_fc1[u];
            #pragma unroll 8
            for (int k = 0; k < HID; ++k) acc = fmaf(h1s[rr][k], W_fc1[u*HID + k], acc);
            part[0][rr][u] = fmaxf(acc, 0.f);
        }
        __syncthreads();
        if (tid < BB) {
            float acc = b_fc2[0];
            #pragma unroll 8
            for (int u = 0; u < 64; ++u) acc = fmaf(part[0][tid][u], W_fc2[u], acc);
            out[row0 + tid] = acc;
        }
    }
}

extern "C" void kernel_launch(void* const* d_in, const int* in_sizes, int n_in,
                              void* d_out, int out_size, void* d_ws, size_t ws_size,
                              hipStream_t stream)
{
    const float* x     = (const float*)d_in[0];
    const float* W_emb = (const float*)d_in[1];
    const float* b_emb = (const float*)d_in[2];
    const float* W_ih0 = (const float*)d_in[3];
    const float* W_hh0 = (const float*)d_in[4];
    const float* b_ih0 = (const float*)d_in[5];
    const float* b_hh0 = (const float*)d_in[6];
    const float* W_ih1 = (const float*)d_in[7];
    const float* W_hh1 = (const float*)d_in[8];
    const float* b_ih1 = (const float*)d_in[9];
    const float* b_hh1 = (const float*)d_in[10];
    const float* W_fc1 = (const float*)d_in[11];
    const float* b_fc1 = (const float*)d_in[12];
    const float* W_fc2 = (const float*)d_in[13];
    const float* b_fc2 = (const float*)d_in[14];
    float* out = (float*)d_out;

    float* out0;
    hipGetSymbolAddress((void**)&out0, HIP_SYMBOL(g_out0));

    prep_kernel<<<2, 256, 0, stream>>>(W_emb, b_emb, W_ih0, W_hh0, b_ih0, b_hh0,
                                       W_ih1, W_hh1, b_ih1, b_hh1);
    lstm_l0<<<2048 / BB, NT, 0, stream>>>(x, out0);

    const int projBlocks = 2048 * TC / BROWS;   // 18432
    for (int c = 0; c < TS / TC; ++c) {
        proj1<<<projBlocks, BNT, 0, stream>>>(c * TC);
        lstm_l1<<<2048 / BB, NT, 0, stream>>>(c * TC, (c == TS / TC - 1) ? 1 : 0,
                                              W_fc1, b_fc1, W_fc2, b_fc2, out);
    }
}